// Round 6
// baseline (402.275 us; speedup 1.0000x reference)
//
#include <hip/hip_runtime.h>
#include <math.h>

#define NNODES 100000
#define NEDGES 1600000
#define ETOT   (NEDGES + NNODES)   // self-loops appended

// bucket-major CSR build
#define BSZ   128                         // dst nodes per bucket (dst >> 7)
#define KBUCK ((NNODES + BSZ - 1) / BSZ)  // 782 buckets
#define CAP   2816                        // max TOTAL entries per bucket
#define NSUB  8                           // per-XCD sub-buckets
#define CAPS  768                         // per sub-bucket (survives XCD skew; R6 lesson)
#define CPAD  16                          // counter padding (one per 64B line)

#define GEMMB 1563                        // gemm0 blocks (64 nodes each)
#define EPT   4                           // edges per thread in bucket half
#define BUCKB ((ETOT + 1024 - 1) / 1024)  // 1661 bucket blocks
#define GGRP  ((GEMMB + 7) / 8)           // 196 gemm groups-of-8
#define BGRP  ((BUCKB + 7) / 8)           // 208 bucket groups-of-8

__device__ __forceinline__ int xcc_id() {
    int x;
    asm volatile("s_getreg_b32 %0, hwreg(HW_REG_XCC_ID)" : "=s"(x));
    return x & (NSUB - 1);
}

// fp32 -> bf16 with round-to-nearest-even (bit-level, no NaN inputs here)
__device__ __forceinline__ unsigned short f2bf(float f) {
    unsigned u = __float_as_uint(f);
    return (unsigned short)((u + 0x7FFFu + ((u >> 16) & 1u)) >> 16);
}

// ===========================================================================
__global__ void zero_cnt(int* __restrict__ cnt) {
    int i = blockIdx.x * blockDim.x + threadIdx.x;
    if (i < KBUCK * NSUB * CPAD) cnt[i] = 0;
}

// ---------------------------------------------------------------------------
// bucket half: append (dst-low, src) to XCD-local sub-bucket. 4-edge ILP.
__device__ __forceinline__ void bucket_body(int bb, const int* __restrict__ ei,
                                            int* __restrict__ cnt,
                                            unsigned int* __restrict__ stage) {
    const int t = threadIdx.x;
    const int xg = xcc_id();
#pragma unroll
    for (int r = 0; r < EPT; ++r) {
        int e = bb * 1024 + r * 256 + t;
        if (e < ETOT) {
            int src, dst;
            if (e < NEDGES) { src = ei[e]; dst = ei[NEDGES + e]; }
            else            { src = dst = e - NEDGES; }
            int sb = (dst >> 7) * NSUB + xg;
            int pos = atomicAdd(&cnt[sb * CPAD], 1);
            if (pos < CAPS)
                stage[(size_t)sb * CAPS + pos] =
                    ((unsigned)(dst & 127) << 24) | (unsigned)src;
        }
    }
}

// ---------------------------------------------------------------------------
// gemm half: h0 = x @ W0.T (64 out-ch, stored bf16) + attention scalars.
// Full-K LDS staging + 3-deep x register prefetch pipeline.
__device__ __forceinline__ void gemm0_body(int gb, const float* __restrict__ x,
                                           const float* __restrict__ W,
                                           const float* __restrict__ att,
                                           unsigned short* __restrict__ h0b,
                                           float* __restrict__ ai,
                                           float* __restrict__ aj) {
    __shared__ float Wt[128 * 68];
    const int tid = threadIdx.x;
    const int nb = gb * 64;

    const int lane = tid & 63;
    const int w    = tid >> 6;
    const int ocg  = lane & 15;          // owns out-ch ocg*4 .. ocg*4+3
    const int ng   = lane >> 4;
    const int nodeLocal = w * 16 + ng * 4;

    const float* xp[4];
#pragma unroll
    for (int j = 0; j < 4; ++j) {
        int node = nb + nodeLocal + j;
        xp[j] = x + (size_t)(node < NNODES ? node : NNODES - 1) * 128;
    }

    // x pipeline issued BEFORE W staging (overlaps stage + barrier)
    float4 xa[4], xb[4], xc[4];
#pragma unroll
    for (int j = 0; j < 4; ++j) {
        xa[j] = *(const float4*)(xp[j] + 0);
        xb[j] = *(const float4*)(xp[j] + 4);
        xc[j] = *(const float4*)(xp[j] + 8);
    }

    for (int i = tid; i < 128 * 64; i += 256) {
        int oc = i >> 7, k = i & 127;
        Wt[k * 68 + oc] = W[i];
    }
    __syncthreads();

    float4 acc[4];
#pragma unroll
    for (int j = 0; j < 4; ++j) acc[j] = make_float4(0.f, 0.f, 0.f, 0.f);

#pragma unroll 4
    for (int k4 = 0; k4 < 32; ++k4) {
        const int kb = k4 * 4;
        int kpf = kb + 12; if (kpf > 124) kpf = 124;
        float4 xn0 = *(const float4*)(xp[0] + kpf);
        float4 xn1 = *(const float4*)(xp[1] + kpf);
        float4 xn2 = *(const float4*)(xp[2] + kpf);
        float4 xn3 = *(const float4*)(xp[3] + kpf);
        float4 wv0 = *(const float4*)&Wt[(kb + 0) * 68 + ocg * 4];
        float4 wv1 = *(const float4*)&Wt[(kb + 1) * 68 + ocg * 4];
        float4 wv2 = *(const float4*)&Wt[(kb + 2) * 68 + ocg * 4];
        float4 wv3 = *(const float4*)&Wt[(kb + 3) * 68 + ocg * 4];
#pragma unroll
        for (int j = 0; j < 4; ++j) {
            float4 xv = xa[j];
            acc[j].x += xv.x * wv0.x + xv.y * wv1.x + xv.z * wv2.x + xv.w * wv3.x;
            acc[j].y += xv.x * wv0.y + xv.y * wv1.y + xv.z * wv2.y + xv.w * wv3.y;
            acc[j].z += xv.x * wv0.z + xv.y * wv1.z + xv.z * wv2.z + xv.w * wv3.z;
            acc[j].w += xv.x * wv0.w + xv.y * wv1.w + xv.z * wv2.w + xv.w * wv3.w;
        }
        xa[0] = xb[0]; xa[1] = xb[1]; xa[2] = xb[2]; xa[3] = xb[3];
        xb[0] = xc[0]; xb[1] = xc[1]; xb[2] = xc[2]; xb[3] = xc[3];
        xc[0] = xn0;   xc[1] = xn1;   xc[2] = xn2;   xc[3] = xn3;
    }

    const int ocb = ocg * 4;
    float ati[4], atj[4];
#pragma unroll
    for (int i = 0; i < 4; ++i) {
        ati[i] = att[ocb + i];
        atj[i] = att[64 + ocb + i];
    }

#pragma unroll
    for (int j = 0; j < 4; ++j) {
        int nodeG = nb + nodeLocal + j;
        float pai = acc[j].x * ati[0] + acc[j].y * ati[1] + acc[j].z * ati[2] + acc[j].w * ati[3];
        float paj = acc[j].x * atj[0] + acc[j].y * atj[1] + acc[j].z * atj[2] + acc[j].w * atj[3];
#pragma unroll
        for (int off = 1; off < 16; off <<= 1) {
            pai += __shfl_xor(pai, off, 64);
            paj += __shfl_xor(paj, off, 64);
        }
        if (nodeG < NNODES) {
            unsigned p0 = ((unsigned)f2bf(acc[j].y) << 16) | f2bf(acc[j].x);
            unsigned p1 = ((unsigned)f2bf(acc[j].w) << 16) | f2bf(acc[j].z);
            *(uint2*)&h0b[(size_t)nodeG * 64 + ocb] = make_uint2(p0, p1);
            if (ocg == 0) { ai[nodeG] = pai; aj[nodeG] = paj; }
        }
    }
}

// ---------------------------------------------------------------------------
// Fused heterogeneous kernel (bucket ∥ gemm0; overlap is real, R4 lesson)
__global__ __launch_bounds__(256) void fusedA(
        const int* __restrict__ ei, int* __restrict__ cnt,
        unsigned int* __restrict__ stage,
        const float* __restrict__ x, const float* __restrict__ W0,
        const float* __restrict__ att0,
        unsigned short* __restrict__ h0b, float* __restrict__ ai0,
        float* __restrict__ aj0) {
    const int bid = blockIdx.x;
    const int grp = bid >> 3, sub = bid & 7;
    if ((grp & 1) && (grp >> 1) < GGRP) {
        int g = (grp >> 1) * 8 + sub;
        if (g < GEMMB) gemm0_body(g, x, W0, att0, h0b, ai0, aj0);
    } else {
        int bg = grp - min(GGRP, (grp + 1) >> 1);
        int bb = bg * 8 + sub;
        if (bb < BUCKB) bucket_body(bb, ei, cnt, stage);
    }
}

// ===========================================================================
__global__ void bucket_scan(const int* __restrict__ cnt, int* __restrict__ bstart) {
    __shared__ int wsum[16];
    const int t = threadIdx.x;                      // 1024 threads
    int x = 0;
    if (t < KBUCK) {
#pragma unroll
        for (int s = 0; s < NSUB; ++s) x += min(cnt[(t * NSUB + s) * CPAD], CAPS);
    }
    int lane = t & 63, w = t >> 6;
    int inc = x;
#pragma unroll
    for (int off = 1; off < 64; off <<= 1) {
        int u = __shfl_up(inc, off, 64);
        if (lane >= off) inc += u;
    }
    if (lane == 63) wsum[w] = inc;
    __syncthreads();
    if (t == 0) {
        int s = 0;
#pragma unroll
        for (int j = 0; j < 16; ++j) { int y = wsum[j]; wsum[j] = s; s += y; }
    }
    __syncthreads();
    int excl = inc - x + wsum[w];
    if (t < KBUCK) bstart[t] = excl;
    if (t == KBUCK) bstart[KBUCK] = excl;
}

// ---------------------------------------------------------------------------
// R6: scatter also computes layer-0 edge alpha = exp(leaky(ai[dst]+aj[src]))
// (it touches every edge anyway; ai staged in LDS, aj 4B gather, expf ONCE).
__global__ __launch_bounds__(256) void bucket_scatter(
        const int* __restrict__ cnt, const int* __restrict__ bstart,
        const unsigned int* __restrict__ stage, int* __restrict__ rowstart,
        int* __restrict__ csr_src, float* __restrict__ csr_alpha,
        const float* __restrict__ ai, const float* __restrict__ aj) {
    __shared__ unsigned int ent[CAP];
    __shared__ int hist[BSZ];
    __shared__ float aiL[BSZ];
    __shared__ int scnt[NSUB];
    __shared__ int soff[NSUB + 1];
    __shared__ int wtot;
    const int b = blockIdx.x, t = threadIdx.x;
    const int n0 = b * BSZ;
    const int base = bstart[b];

    if (t < BSZ) {
        hist[t] = 0;
        int node = n0 + t;
        aiL[t] = (node < NNODES) ? ai[node] : 0.0f;
    }
    if (t < NSUB) scnt[t] = min(cnt[(b * NSUB + t) * CPAD], CAPS);
    __syncthreads();
    if (t == 0) {
        int s = 0;
#pragma unroll
        for (int x = 0; x < NSUB; ++x) { soff[x] = s; s += scnt[x]; }
        soff[NSUB] = s;
    }
    __syncthreads();

#pragma unroll
    for (int x = 0; x < NSUB; ++x) {
        const int cx = scnt[x];
        const int ox = soff[x];
        const unsigned int* sp = stage + (size_t)(b * NSUB + x) * CAPS;
        for (int i = t; i < cx; i += 256) {
            unsigned int v = sp[i];
            ent[ox + i] = v;
            atomicAdd(&hist[v >> 24], 1);
        }
    }
    __syncthreads();
    const int c = soff[NSUB];

    int lane = t & 63, w = t >> 6;
    int v = (t < BSZ) ? hist[t] : 0;
    int inc = v;
#pragma unroll
    for (int off = 1; off < 64; off <<= 1) {
        int u = __shfl_up(inc, off, 64);
        if (lane >= off) inc += u;
    }
    if (t == 63) wtot = inc;
    __syncthreads();
    int excl = inc - v + ((w == 1) ? wtot : 0);
    if (t < BSZ) {
        int node = n0 + t;
        if (node <= NNODES) rowstart[node] = base + excl;
    }
    __syncthreads();
    if (t < BSZ) hist[t] = excl;
    __syncthreads();
    for (int i = t; i < c; i += 256) {
        unsigned int e = ent[i];
        int dl  = e >> 24;
        int src = (int)(e & 0xFFFFFFu);
        int pos = atomicAdd(&hist[dl], 1);
        float tv = aiL[dl] + aj[src];
        tv = (tv > 0.0f) ? tv : 0.2f * tv;
        csr_src[base + pos]   = src;
        csr_alpha[base + pos] = __expf(tv);
    }
}

// ===========================================================================
// R6: layer-1 alpha pass — one coalesced 64-lane sweep per row chunk.
// alpha2 = exp(leaky(ai1[dst] + aj1[src])). 8x fewer wave-inst than doing it
// redundantly inside agg_lsm's 8-lane groups.
// ===========================================================================
__global__ __launch_bounds__(256) void alpha1_k(
        const int* __restrict__ rowstart, const int* __restrict__ csr_src,
        const float* __restrict__ ai1, const float* __restrict__ aj1,
        float* __restrict__ csr_alpha2) {
    const int lane = threadIdx.x & 63;
    const int wid  = threadIdx.x >> 6;
    const int n = blockIdx.x * 4 + wid;
    if (n >= NNODES) return;
    const int start = rowstart[n];
    const int end   = rowstart[n + 1];
    const float ain = ai1[n];
    for (int c = start + lane; c < end; c += 64) {
        int s = csr_src[c];
        float t = ain + aj1[s];
        t = (t > 0.0f) ? t : 0.2f * t;
        csr_alpha2[c] = __expf(t);
    }
}

// ===========================================================================
// Layer-0 aggregation + fused gemm1 -> bf16 h1 + layer-1 attention scalars.
// R6: alpha precomputed -> coalesced load once per chunk, esum counted once,
// trip body = 2 shfl + h0b gather + unpack + FMA (no aj gather, no expf).
// ===========================================================================
__global__ __launch_bounds__(256) void agg_gemm1(
        const int* __restrict__ rowstart, const int* __restrict__ csr_src,
        const float* __restrict__ csr_alpha, const unsigned short* __restrict__ h0b,
        const float* __restrict__ W1, const float* __restrict__ att1,
        unsigned short* __restrict__ h1b, float* __restrict__ ai1,
        float* __restrict__ aj1) {
    __shared__ float  W1L[64 * 68];     // oc-major, stride 68 (2-way banks: free)
    __shared__ float  rowbuf[4][64];    // per-wave combined row

    const int tid = threadIdx.x;
    for (int i = tid; i < 64 * 64; i += 256) {
        int oc = i >> 6, k = i & 63;
        W1L[oc * 68 + k] = (oc < 40) ? W1[oc * 64 + k] : 0.0f;
    }
    __syncthreads();

    const int lane = tid & 63;
    const int wid  = tid >> 6;
    const int n = blockIdx.x * 4 + wid;
    if (n >= NNODES) return;

    const int start = rowstart[n];
    const int end   = rowstart[n + 1];

    const int cg = lane & 7;            // 8 channel-groups of 8 ch
    const int sg = lane >> 3;           // 8 edge slots
    const int cgo = cg << 3;            // channel offset
    float4 accA = make_float4(0.f, 0.f, 0.f, 0.f);
    float4 accB = make_float4(0.f, 0.f, 0.f, 0.f);
    float  esum = 0.0f;

    for (int c = start; c < end; c += 64) {
        int rem = end - c;
        int cnt = (rem < 64) ? rem : 64;            // wave-uniform
        int   s  = 0;
        float av = 0.0f;
        if (lane < cnt) {
            s  = csr_src[c + lane];
            av = csr_alpha[c + lane];
        }
        esum += av;                                 // each edge exactly once
        for (int j0 = 0; j0 < cnt; j0 += 8) {
            int j  = j0 + sg;
            int   sj = __shfl(s,  j, 64);
            float a  = __shfl(av, j, 64);
            if (j < cnt) {
                uint4 hv = *(const uint4*)&h0b[(unsigned)(sj << 6) + cgo];
                float c0 = __uint_as_float(hv.x << 16);
                float c1 = __uint_as_float(hv.x & 0xFFFF0000u);
                float c2 = __uint_as_float(hv.y << 16);
                float c3 = __uint_as_float(hv.y & 0xFFFF0000u);
                float c4 = __uint_as_float(hv.z << 16);
                float c5 = __uint_as_float(hv.z & 0xFFFF0000u);
                float c6 = __uint_as_float(hv.w << 16);
                float c7 = __uint_as_float(hv.w & 0xFFFF0000u);
                accA.x = fmaf(a, c0, accA.x);
                accA.y = fmaf(a, c1, accA.y);
                accA.z = fmaf(a, c2, accA.z);
                accA.w = fmaf(a, c3, accA.w);
                accB.x = fmaf(a, c4, accB.x);
                accB.y = fmaf(a, c5, accB.y);
                accB.z = fmaf(a, c6, accB.z);
                accB.w = fmaf(a, c7, accB.w);
            }
        }
    }
#pragma unroll
    for (int off = 32; off > 0; off >>= 1) esum += __shfl_xor(esum, off, 64);
    const float inv = 1.0f / esum;
#pragma unroll
    for (int off = 8; off < 64; off <<= 1) {        // reduce over 8 edge slots
        accA.x += __shfl_xor(accA.x, off, 64);
        accA.y += __shfl_xor(accA.y, off, 64);
        accA.z += __shfl_xor(accA.z, off, 64);
        accA.w += __shfl_xor(accA.w, off, 64);
        accB.x += __shfl_xor(accB.x, off, 64);
        accB.y += __shfl_xor(accB.y, off, 64);
        accB.z += __shfl_xor(accB.z, off, 64);
        accB.w += __shfl_xor(accB.w, off, 64);
    }
    // normalize + relu, park row in LDS
    if (sg == 0) {
        float4 rA, rB;
        rA.x = fmaxf(accA.x * inv, 0.0f);
        rA.y = fmaxf(accA.y * inv, 0.0f);
        rA.z = fmaxf(accA.z * inv, 0.0f);
        rA.w = fmaxf(accA.w * inv, 0.0f);
        rB.x = fmaxf(accB.x * inv, 0.0f);
        rB.y = fmaxf(accB.y * inv, 0.0f);
        rB.z = fmaxf(accB.z * inv, 0.0f);
        rB.w = fmaxf(accB.w * inv, 0.0f);
        *(float4*)&rowbuf[wid][cgo]     = rA;
        *(float4*)&rowbuf[wid][cgo + 4] = rB;
    }

    // ---- fused gemm1: h1[n,oc] = sum_k row[k] * W1[oc,k] ----
    const int oc = lane;                 // lanes 40..63 hit zero-padded W1 rows
    float hacc = 0.0f;
#pragma unroll
    for (int k4 = 0; k4 < 16; ++k4) {
        float4 rv = *(const float4*)&rowbuf[wid][k4 * 4];       // broadcast
        float4 wv = *(const float4*)&W1L[oc * 68 + k4 * 4];
        hacc = fmaf(rv.x, wv.x, hacc);
        hacc = fmaf(rv.y, wv.y, hacc);
        hacc = fmaf(rv.z, wv.z, hacc);
        hacc = fmaf(rv.w, wv.w, hacc);
    }

    const bool ocOK = (oc < 40);
    if (ocOK) h1b[(size_t)n * 40 + oc] = f2bf(hacc);
    float pai = ocOK ? hacc * att1[oc]      : 0.0f;
    float paj = ocOK ? hacc * att1[40 + oc] : 0.0f;
#pragma unroll
    for (int off = 1; off < 64; off <<= 1) {
        pai += __shfl_xor(pai, off, 64);
        paj += __shfl_xor(paj, off, 64);
    }
    if (lane == 0) { ai1[n] = pai; aj1[n] = paj; }
}

// ===========================================================================
// Layer-1 aggregation (bf16 h1, 40 ch) + log_softmax. R6: precomputed alpha2.
// ===========================================================================
__global__ __launch_bounds__(256) void agg_lsm(
        const int* __restrict__ rowstart, const int* __restrict__ csr_src,
        const float* __restrict__ csr_alpha2,
        const unsigned short* __restrict__ h1b, float* __restrict__ out) {
    const int lane = threadIdx.x & 63;
    const int wid  = threadIdx.x >> 6;
    const int n = blockIdx.x * 4 + wid;
    if (n >= NNODES) return;

    const int start = rowstart[n];
    const int end   = rowstart[n + 1];

    const int  cg   = lane & 7;
    const int  sg   = lane >> 3;
    const bool chOK = (cg < 5);         // 40 channels = 5 uint4 chunks
    float4 accA = make_float4(0.f, 0.f, 0.f, 0.f);
    float4 accB = make_float4(0.f, 0.f, 0.f, 0.f);
    float  esum = 0.0f;

    for (int c = start; c < end; c += 64) {
        int rem = end - c;
        int cnt = (rem < 64) ? rem : 64;
        int   s  = 0;
        float av = 0.0f;
        if (lane < cnt) {
            s  = csr_src[c + lane];
            av = csr_alpha2[c + lane];
        }
        esum += av;                                 // each edge exactly once
        for (int j0 = 0; j0 < cnt; j0 += 8) {
            int j  = j0 + sg;
            int   sj = __shfl(s,  j, 64);
            float a  = __shfl(av, j, 64);
            if (chOK && j < cnt) {
                uint4 hv = *(const uint4*)&h1b[(unsigned)(sj * 40) + (cg << 3)];
                float c0 = __uint_as_float(hv.x << 16);
                float c1 = __uint_as_float(hv.x & 0xFFFF0000u);
                float c2 = __uint_as_float(hv.y << 16);
                float c3 = __uint_as_float(hv.y & 0xFFFF0000u);
                float c4 = __uint_as_float(hv.z << 16);
                float c5 = __uint_as_float(hv.z & 0xFFFF0000u);
                float c6 = __uint_as_float(hv.w << 16);
                float c7 = __uint_as_float(hv.w & 0xFFFF0000u);
                accA.x = fmaf(a, c0, accA.x);
                accA.y = fmaf(a, c1, accA.y);
                accA.z = fmaf(a, c2, accA.z);
                accA.w = fmaf(a, c3, accA.w);
                accB.x = fmaf(a, c4, accB.x);
                accB.y = fmaf(a, c5, accB.y);
                accB.z = fmaf(a, c6, accB.z);
                accB.w = fmaf(a, c7, accB.w);
            }
        }
    }
#pragma unroll
    for (int off = 32; off > 0; off >>= 1) esum += __shfl_xor(esum, off, 64);
    const float inv = 1.0f / esum;
#pragma unroll
    for (int off = 8; off < 64; off <<= 1) {
        accA.x += __shfl_xor(accA.x, off, 64);
        accA.y += __shfl_xor(accA.y, off, 64);
        accA.z += __shfl_xor(accA.z, off, 64);
        accA.w += __shfl_xor(accA.w, off, 64);
        accB.x += __shfl_xor(accB.x, off, 64);
        accB.y += __shfl_xor(accB.y, off, 64);
        accB.z += __shfl_xor(accB.z, off, 64);
        accB.w += __shfl_xor(accB.w, off, 64);
    }
    accA.x *= inv; accA.y *= inv; accA.z *= inv; accA.w *= inv;
    accB.x *= inv; accB.y *= inv; accB.z *= inv; accB.w *= inv;

    // log_softmax over 40 values (5 uint4 chunks in lanes cg<5; values
    // replicated across all 8 sg groups after the xor-reduce)
    float mx = -INFINITY;
    if (chOK) {
        mx = fmaxf(fmaxf(fmaxf(accA.x, accA.y), fmaxf(accA.z, accA.w)),
                   fmaxf(fmaxf(accB.x, accB.y), fmaxf(accB.z, accB.w)));
    }
#pragma unroll
    for (int off = 1; off < 8; off <<= 1) mx = fmaxf(mx, __shfl_xor(mx, off, 64));
    float sm = 0.0f;
    if (chOK) {
        sm = __expf(accA.x - mx) + __expf(accA.y - mx) +
             __expf(accA.z - mx) + __expf(accA.w - mx) +
             __expf(accB.x - mx) + __expf(accB.y - mx) +
             __expf(accB.z - mx) + __expf(accB.w - mx);
    }
#pragma unroll
    for (int off = 1; off < 8; off <<= 1) sm += __shfl_xor(sm, off, 64);
    float ls = mx + logf(sm);
    if (sg == 0 && chOK) {
        float4 oA = make_float4(accA.x - ls, accA.y - ls, accA.z - ls, accA.w - ls);
        float4 oB = make_float4(accB.x - ls, accB.y - ls, accB.z - ls, accB.w - ls);
        *(float4*)&out[(size_t)n * 40 + (cg << 3)]     = oA;
        *(float4*)&out[(size_t)n * 40 + (cg << 3) + 4] = oB;
    }
}

// ===========================================================================
extern "C" void kernel_launch(void* const* d_in, const int* in_sizes, int n_in,
                              void* d_out, int out_size, void* d_ws, size_t ws_size,
                              hipStream_t stream) {
    const float* x    = (const float*)d_in[0];
    const int*   ei   = (const int*)  d_in[1];
    const float* W0   = (const float*)d_in[2];
    const float* att0 = (const float*)d_in[3];
    const float* W1   = (const float*)d_in[4];
    const float* att1 = (const float*)d_in[5];
    float* out = (float*)d_out;

    // workspace layout (16B-aligned segments)
    int* wi = (int*)d_ws;
    int*  cnt      = wi;                        // 100352
    int*  bstart   = cnt + 100352;              // 1024
    int*  rowstart = bstart + 1024;             // 100352
    unsigned int* stage = (unsigned int*)(rowstart + 100352);     // KBUCK*NSUB*CAPS
    int*  csr_src  = (int*)(stage + (size_t)KBUCK * NSUB * CAPS); // 1,700,096
    float* csr_alpha = (float*)(csr_src + 1700096);               // 1,700,096 (6.8MB)
    unsigned short* h0b = (unsigned short*)(csr_alpha + 1700096); // N*64 bf16 (12.8MB)
    unsigned short* h1b = h0b + (size_t)NNODES * 64;              // N*40 bf16 (8MB)
    float* fbase = (float*)(h1b + (size_t)NNODES * 40);
    float* ai0 = fbase;
    float* aj0 = ai0 + 100352;
    float* ai1 = aj0 + 100352;
    float* aj1 = ai1 + 100352;
    // layer-1 alpha aliases the (dead after scatter) stage buffer
    float* csr_alpha2 = (float*)stage;

    const int B = 256;
    const int aggGrid = (NNODES + 3) / 4;
    const int fusedGrid = (GGRP + BGRP) * 8;

    // ---- CSR build (bucket half) fused with layer-0 GEMM (independent) ----
    zero_cnt<<<(KBUCK * NSUB * CPAD + B - 1) / B, B, 0, stream>>>(cnt);
    fusedA<<<fusedGrid, B, 0, stream>>>(ei, cnt, stage, x, W0, att0, h0b, ai0, aj0);
    bucket_scan<<<1, 1024, 0, stream>>>(cnt, bstart);
    bucket_scatter<<<KBUCK, B, 0, stream>>>(cnt, bstart, stage, rowstart,
                                            csr_src, csr_alpha, ai0, aj0);

    // ---- layer-0 aggregation + fused gemm1 + layer-1 attention scalars ----
    agg_gemm1<<<aggGrid, B, 0, stream>>>(rowstart, csr_src, csr_alpha, h0b,
                                         W1, att1, h1b, ai1, aj1);

    // ---- layer-1 alpha pass, then aggregation + log_softmax ----
    alpha1_k<<<aggGrid, B, 0, stream>>>(rowstart, csr_src, ai1, aj1, csr_alpha2);
    agg_lsm<<<aggGrid, B, 0, stream>>>(rowstart, csr_src, csr_alpha2, h1b, out);
}

// Round 9
// 400.179 us; speedup vs baseline: 1.0052x; 1.0052x over previous
//
#include <hip/hip_runtime.h>
#include <math.h>

#define NNODES 100000
#define NEDGES 1600000
#define ETOT   (NEDGES + NNODES)   // self-loops appended

// bucket-major CSR build
#define BSZ   128                         // dst nodes per bucket (dst >> 7)
#define KBUCK ((NNODES + BSZ - 1) / BSZ)  // 782 buckets
#define CAP   2816                        // max TOTAL entries per bucket
#define NSUB  8                           // per-XCD sub-buckets
#define CAPS  768                         // per sub-bucket
#define CPAD  16                          // counter padding (one per 64B line)

#define GEMMB 1563                        // gemm0 blocks (64 nodes each)
#define EPT   4                           // edges per thread in bucket half
#define BUCKB ((ETOT + 1024 - 1) / 1024)  // 1661 bucket blocks
#define GGRP  ((GEMMB + 7) / 8)           // 196 gemm groups-of-8
#define BGRP  ((BUCKB + 7) / 8)           // 208 bucket groups-of-8

__device__ __forceinline__ int xcc_id() {
    int x;
    asm volatile("s_getreg_b32 %0, hwreg(HW_REG_XCC_ID)" : "=s"(x));
    return x & (NSUB - 1);
}

// fp32 -> bf16 with round-to-nearest-even (bit-level, no NaN inputs here)
__device__ __forceinline__ unsigned short f2bf(float f) {
    unsigned u = __float_as_uint(f);
    return (unsigned short)((u + 0x7FFFu + ((u >> 16) & 1u)) >> 16);
}

// ===========================================================================
__global__ void zero_cnt(int* __restrict__ cnt) {
    int i = blockIdx.x * blockDim.x + threadIdx.x;
    if (i < KBUCK * NSUB * CPAD) cnt[i] = 0;
}

// ---------------------------------------------------------------------------
// bucket half: append (dst-low, src) to XCD-local sub-bucket. 4-edge ILP.
__device__ __forceinline__ void bucket_body(int bb, const int* __restrict__ ei,
                                            int* __restrict__ cnt,
                                            unsigned int* __restrict__ stage) {
    const int t = threadIdx.x;
    const int xg = xcc_id();
#pragma unroll
    for (int r = 0; r < EPT; ++r) {
        int e = bb * 1024 + r * 256 + t;
        if (e < ETOT) {
            int src, dst;
            if (e < NEDGES) { src = ei[e]; dst = ei[NEDGES + e]; }
            else            { src = dst = e - NEDGES; }
            int sb = (dst >> 7) * NSUB + xg;
            int pos = atomicAdd(&cnt[sb * CPAD], 1);
            if (pos < CAPS)
                stage[(size_t)sb * CAPS + pos] =
                    ((unsigned)(dst & 127) << 24) | (unsigned)src;
        }
    }
}

// ---------------------------------------------------------------------------
// gemm half: h0 = x @ W0.T (64 out-ch, stored bf16) + attention scalars.
// Full-K LDS staging + 3-deep x register prefetch pipeline.
__device__ __forceinline__ void gemm0_body(int gb, const float* __restrict__ x,
                                           const float* __restrict__ W,
                                           const float* __restrict__ att,
                                           unsigned short* __restrict__ h0b,
                                           float* __restrict__ ai,
                                           float* __restrict__ aj) {
    __shared__ float Wt[128 * 68];
    const int tid = threadIdx.x;
    const int nb = gb * 64;

    const int lane = tid & 63;
    const int w    = tid >> 6;
    const int ocg  = lane & 15;          // owns out-ch ocg*4 .. ocg*4+3
    const int ng   = lane >> 4;
    const int nodeLocal = w * 16 + ng * 4;

    const float* xp[4];
#pragma unroll
    for (int j = 0; j < 4; ++j) {
        int node = nb + nodeLocal + j;
        xp[j] = x + (size_t)(node < NNODES ? node : NNODES - 1) * 128;
    }

    // x pipeline issued BEFORE W staging (overlaps stage + barrier)
    float4 xa[4], xb[4], xc[4];
#pragma unroll
    for (int j = 0; j < 4; ++j) {
        xa[j] = *(const float4*)(xp[j] + 0);
        xb[j] = *(const float4*)(xp[j] + 4);
        xc[j] = *(const float4*)(xp[j] + 8);
    }

    for (int i = tid; i < 128 * 64; i += 256) {
        int oc = i >> 7, k = i & 127;
        Wt[k * 68 + oc] = W[i];
    }
    __syncthreads();

    float4 acc[4];
#pragma unroll
    for (int j = 0; j < 4; ++j) acc[j] = make_float4(0.f, 0.f, 0.f, 0.f);

#pragma unroll 4
    for (int k4 = 0; k4 < 32; ++k4) {
        const int kb = k4 * 4;
        int kpf = kb + 12; if (kpf > 124) kpf = 124;
        float4 xn0 = *(const float4*)(xp[0] + kpf);
        float4 xn1 = *(const float4*)(xp[1] + kpf);
        float4 xn2 = *(const float4*)(xp[2] + kpf);
        float4 xn3 = *(const float4*)(xp[3] + kpf);
        float4 wv0 = *(const float4*)&Wt[(kb + 0) * 68 + ocg * 4];
        float4 wv1 = *(const float4*)&Wt[(kb + 1) * 68 + ocg * 4];
        float4 wv2 = *(const float4*)&Wt[(kb + 2) * 68 + ocg * 4];
        float4 wv3 = *(const float4*)&Wt[(kb + 3) * 68 + ocg * 4];
#pragma unroll
        for (int j = 0; j < 4; ++j) {
            float4 xv = xa[j];
            acc[j].x += xv.x * wv0.x + xv.y * wv1.x + xv.z * wv2.x + xv.w * wv3.x;
            acc[j].y += xv.x * wv0.y + xv.y * wv1.y + xv.z * wv2.y + xv.w * wv3.y;
            acc[j].z += xv.x * wv0.z + xv.y * wv1.z + xv.z * wv2.z + xv.w * wv3.z;
            acc[j].w += xv.x * wv0.w + xv.y * wv1.w + xv.z * wv2.w + xv.w * wv3.w;
        }
        xa[0] = xb[0]; xa[1] = xb[1]; xa[2] = xb[2]; xa[3] = xb[3];
        xb[0] = xc[0]; xb[1] = xc[1]; xb[2] = xc[2]; xb[3] = xc[3];
        xc[0] = xn0;   xc[1] = xn1;   xc[2] = xn2;   xc[3] = xn3;
    }

    const int ocb = ocg * 4;
    float ati[4], atj[4];
#pragma unroll
    for (int i = 0; i < 4; ++i) {
        ati[i] = att[ocb + i];
        atj[i] = att[64 + ocb + i];
    }

#pragma unroll
    for (int j = 0; j < 4; ++j) {
        int nodeG = nb + nodeLocal + j;
        float pai = acc[j].x * ati[0] + acc[j].y * ati[1] + acc[j].z * ati[2] + acc[j].w * ati[3];
        float paj = acc[j].x * atj[0] + acc[j].y * atj[1] + acc[j].z * atj[2] + acc[j].w * atj[3];
#pragma unroll
        for (int off = 1; off < 16; off <<= 1) {
            pai += __shfl_xor(pai, off, 64);
            paj += __shfl_xor(paj, off, 64);
        }
        if (nodeG < NNODES) {
            unsigned p0 = ((unsigned)f2bf(acc[j].y) << 16) | f2bf(acc[j].x);
            unsigned p1 = ((unsigned)f2bf(acc[j].w) << 16) | f2bf(acc[j].z);
            *(uint2*)&h0b[(size_t)nodeG * 64 + ocb] = make_uint2(p0, p1);
            if (ocg == 0) { ai[nodeG] = pai; aj[nodeG] = paj; }
        }
    }
}

// ---------------------------------------------------------------------------
// Fused heterogeneous kernel (bucket ∥ gemm0; overlap is real, R4 lesson)
__global__ __launch_bounds__(256) void fusedA(
        const int* __restrict__ ei, int* __restrict__ cnt,
        unsigned int* __restrict__ stage,
        const float* __restrict__ x, const float* __restrict__ W0,
        const float* __restrict__ att0,
        unsigned short* __restrict__ h0b, float* __restrict__ ai0,
        float* __restrict__ aj0) {
    const int bid = blockIdx.x;
    const int grp = bid >> 3, sub = bid & 7;
    if ((grp & 1) && (grp >> 1) < GGRP) {
        int g = (grp >> 1) * 8 + sub;
        if (g < GEMMB) gemm0_body(g, x, W0, att0, h0b, ai0, aj0);
    } else {
        int bg = grp - min(GGRP, (grp + 1) >> 1);
        int bb = bg * 8 + sub;
        if (bb < BUCKB) bucket_body(bb, ei, cnt, stage);
    }
}

// ===========================================================================
__global__ void bucket_scan(const int* __restrict__ cnt, int* __restrict__ bstart) {
    __shared__ int wsum[16];
    const int t = threadIdx.x;                      // 1024 threads
    int x = 0;
    if (t < KBUCK) {
#pragma unroll
        for (int s = 0; s < NSUB; ++s) x += min(cnt[(t * NSUB + s) * CPAD], CAPS);
    }
    int lane = t & 63, w = t >> 6;
    int inc = x;
#pragma unroll
    for (int off = 1; off < 64; off <<= 1) {
        int u = __shfl_up(inc, off, 64);
        if (lane >= off) inc += u;
    }
    if (lane == 63) wsum[w] = inc;
    __syncthreads();
    if (t == 0) {
        int s = 0;
#pragma unroll
        for (int j = 0; j < 16; ++j) { int y = wsum[j]; wsum[j] = s; s += y; }
    }
    __syncthreads();
    int excl = inc - x + wsum[w];
    if (t < KBUCK) bstart[t] = excl;
    if (t == KBUCK) bstart[KBUCK] = excl;
}

__global__ __launch_bounds__(256) void bucket_scatter(
        const int* __restrict__ cnt, const int* __restrict__ bstart,
        const unsigned int* __restrict__ stage, int* __restrict__ rowstart,
        int* __restrict__ csr_src) {
    __shared__ unsigned int ent[CAP];
    __shared__ int hist[BSZ];
    __shared__ int scnt[NSUB];
    __shared__ int soff[NSUB + 1];
    __shared__ int wtot;
    const int b = blockIdx.x, t = threadIdx.x;
    const int n0 = b * BSZ;
    const int base = bstart[b];

    if (t < BSZ) hist[t] = 0;
    if (t < NSUB) scnt[t] = min(cnt[(b * NSUB + t) * CPAD], CAPS);
    __syncthreads();
    if (t == 0) {
        int s = 0;
#pragma unroll
        for (int x = 0; x < NSUB; ++x) { soff[x] = s; s += scnt[x]; }
        soff[NSUB] = s;
    }
    __syncthreads();

#pragma unroll
    for (int x = 0; x < NSUB; ++x) {
        const int cx = scnt[x];
        const int ox = soff[x];
        const unsigned int* sp = stage + (size_t)(b * NSUB + x) * CAPS;
        for (int i = t; i < cx; i += 256) {
            unsigned int v = sp[i];
            ent[ox + i] = v;
            atomicAdd(&hist[v >> 24], 1);
        }
    }
    __syncthreads();
    const int c = soff[NSUB];

    int lane = t & 63, w = t >> 6;
    int v = (t < BSZ) ? hist[t] : 0;
    int inc = v;
#pragma unroll
    for (int off = 1; off < 64; off <<= 1) {
        int u = __shfl_up(inc, off, 64);
        if (lane >= off) inc += u;
    }
    if (t == 63) wtot = inc;
    __syncthreads();
    int excl = inc - v + ((w == 1) ? wtot : 0);
    if (t < BSZ) {
        int node = n0 + t;
        if (node <= NNODES) rowstart[node] = base + excl;
    }
    __syncthreads();
    if (t < BSZ) hist[t] = excl;
    __syncthreads();
    for (int i = t; i < c; i += 256) {
        unsigned int e = ent[i];
        int pos = atomicAdd(&hist[e >> 24], 1);
        csr_src[base + pos] = (int)(e & 0xFFFFFFu);
    }
}

// ===========================================================================
// Layer-0 aggregation + fused gemm1 -> bf16 h1 + layer-1 attention scalars.
// R8: batched 8-deep gathers (R7 theory) with the shfl-under-divergence bug
// FIXED: every __shfl executes unconditionally on the full wave (ds_bpermute
// from an EXEC-inactive source lane is undefined on CDNA — R7's absmax fail);
// only the dependent load/FMA is guarded.
// ===========================================================================
__global__ __launch_bounds__(256) void agg_gemm1(
        const int* __restrict__ rowstart, const int* __restrict__ csr_src,
        const float* __restrict__ aj,
        const float* __restrict__ ai, const unsigned short* __restrict__ h0b,
        const float* __restrict__ W1, const float* __restrict__ att1,
        unsigned short* __restrict__ h1b, float* __restrict__ ai1,
        float* __restrict__ aj1) {
    __shared__ float  W1L[64 * 68];     // oc-major, stride 68 (2-way banks: free)
    __shared__ float  rowbuf[4][64];    // per-wave combined row

    const int tid = threadIdx.x;
    for (int i = tid; i < 64 * 64; i += 256) {
        int oc = i >> 6, k = i & 63;
        W1L[oc * 68 + k] = (oc < 40) ? W1[oc * 64 + k] : 0.0f;
    }
    __syncthreads();

    const int lane = tid & 63;
    const int wid  = tid >> 6;
    const int n = blockIdx.x * 4 + wid;
    if (n >= NNODES) return;

    const int start = rowstart[n];
    const int end   = rowstart[n + 1];
    const float ain = ai[n];

    const int cg = lane & 7;            // 8 channel-groups of 8 ch
    const int sg = lane >> 3;           // 8 edge slots
    const int cgo = cg << 3;            // channel offset
    float4 accA = make_float4(0.f, 0.f, 0.f, 0.f);
    float4 accB = make_float4(0.f, 0.f, 0.f, 0.f);
    float  esum = 0.0f;

    for (int c = start; c < end; c += 64) {
        int rem = end - c;
        int cnt = (rem < 64) ? rem : 64;            // wave-uniform
        int   s   = 0;
        float ajv = 0.0f;
        if (lane < cnt) {
            s   = csr_src[c + lane];
            ajv = aj[s];                            // own-edge gather (issues now)
        }
        // ---- edge indices: shfl on FULL wave (sources all active) ----
        int sj0 = __shfl(s, 0 * 8 + sg, 64);
        int sj1 = __shfl(s, 1 * 8 + sg, 64);
        int sj2 = __shfl(s, 2 * 8 + sg, 64);
        int sj3 = __shfl(s, 3 * 8 + sg, 64);
        int sj4 = __shfl(s, 4 * 8 + sg, 64);
        int sj5 = __shfl(s, 5 * 8 + sg, 64);
        int sj6 = __shfl(s, 6 * 8 + sg, 64);
        int sj7 = __shfl(s, 7 * 8 + sg, 64);
        // ---- phase 1: issue all h0b gathers (independent, 8-deep) ----
        uint4 h0v, h1v, h2v, h3v, h4v, h5v, h6v, h7v;
#define GATH(T, SJ, HV) \
        if ((T) * 8 + sg < cnt) HV = *(const uint4*)&h0b[(unsigned)((SJ) << 6) + cgo];
        GATH(0, sj0, h0v) GATH(1, sj1, h1v) GATH(2, sj2, h2v) GATH(3, sj3, h3v)
        GATH(4, sj4, h4v) GATH(5, sj5, h5v) GATH(6, sj6, h6v) GATH(7, sj7, h7v)
#undef GATH
        // ---- alpha for own edge (expf overlaps gather latency) ----
        float tv = ain + ajv;
        tv = (tv > 0.0f) ? tv : 0.2f * tv;
        float av = (lane < cnt) ? __expf(tv) : 0.0f;
        esum += av;                                 // each edge exactly once
        // ---- phase 2: unpack + FMA (alpha shfl also full-wave) ----
#define USE(T, HV) \
        { float a = __shfl(av, (T) * 8 + sg, 64); \
          if ((T) * 8 + sg < cnt) { \
            accA.x = fmaf(a, __uint_as_float(HV.x << 16),          accA.x); \
            accA.y = fmaf(a, __uint_as_float(HV.x & 0xFFFF0000u),  accA.y); \
            accA.z = fmaf(a, __uint_as_float(HV.y << 16),          accA.z); \
            accA.w = fmaf(a, __uint_as_float(HV.y & 0xFFFF0000u),  accA.w); \
            accB.x = fmaf(a, __uint_as_float(HV.z << 16),          accB.x); \
            accB.y = fmaf(a, __uint_as_float(HV.z & 0xFFFF0000u),  accB.y); \
            accB.z = fmaf(a, __uint_as_float(HV.w << 16),          accB.z); \
            accB.w = fmaf(a, __uint_as_float(HV.w & 0xFFFF0000u),  accB.w); \
          } }
        USE(0, h0v) USE(1, h1v) USE(2, h2v) USE(3, h3v)
        USE(4, h4v) USE(5, h5v) USE(6, h6v) USE(7, h7v)
#undef USE
    }
#pragma unroll
    for (int off = 32; off > 0; off >>= 1) esum += __shfl_xor(esum, off, 64);
    const float inv = 1.0f / esum;
#pragma unroll
    for (int off = 8; off < 64; off <<= 1) {        // reduce over 8 edge slots
        accA.x += __shfl_xor(accA.x, off, 64);
        accA.y += __shfl_xor(accA.y, off, 64);
        accA.z += __shfl_xor(accA.z, off, 64);
        accA.w += __shfl_xor(accA.w, off, 64);
        accB.x += __shfl_xor(accB.x, off, 64);
        accB.y += __shfl_xor(accB.y, off, 64);
        accB.z += __shfl_xor(accB.z, off, 64);
        accB.w += __shfl_xor(accB.w, off, 64);
    }
    // normalize + relu, park row in LDS
    if (sg == 0) {
        float4 rA, rB;
        rA.x = fmaxf(accA.x * inv, 0.0f);
        rA.y = fmaxf(accA.y * inv, 0.0f);
        rA.z = fmaxf(accA.z * inv, 0.0f);
        rA.w = fmaxf(accA.w * inv, 0.0f);
        rB.x = fmaxf(accB.x * inv, 0.0f);
        rB.y = fmaxf(accB.y * inv, 0.0f);
        rB.z = fmaxf(accB.z * inv, 0.0f);
        rB.w = fmaxf(accB.w * inv, 0.0f);
        *(float4*)&rowbuf[wid][cgo]     = rA;
        *(float4*)&rowbuf[wid][cgo + 4] = rB;
    }

    // ---- fused gemm1: h1[n,oc] = sum_k row[k] * W1[oc,k] ----
    const int oc = lane;                 // lanes 40..63 hit zero-padded W1 rows
    float hacc = 0.0f;
#pragma unroll
    for (int k4 = 0; k4 < 16; ++k4) {
        float4 rv = *(const float4*)&rowbuf[wid][k4 * 4];       // broadcast
        float4 wv = *(const float4*)&W1L[oc * 68 + k4 * 4];
        hacc = fmaf(rv.x, wv.x, hacc);
        hacc = fmaf(rv.y, wv.y, hacc);
        hacc = fmaf(rv.z, wv.z, hacc);
        hacc = fmaf(rv.w, wv.w, hacc);
    }

    const bool ocOK = (oc < 40);
    if (ocOK) h1b[(size_t)n * 40 + oc] = f2bf(hacc);
    float pai = ocOK ? hacc * att1[oc]      : 0.0f;
    float paj = ocOK ? hacc * att1[40 + oc] : 0.0f;
#pragma unroll
    for (int off = 1; off < 64; off <<= 1) {
        pai += __shfl_xor(pai, off, 64);
        paj += __shfl_xor(paj, off, 64);
    }
    if (lane == 0) { ai1[n] = pai; aj1[n] = paj; }
}

// ===========================================================================
// Layer-1 aggregation (bf16 h1, 40 ch) + log_softmax. R8: same batched-gather
// with full-wave shfl fix.
// ===========================================================================
__global__ __launch_bounds__(256) void agg_lsm(
        const int* __restrict__ rowstart, const int* __restrict__ csr_src,
        const float* __restrict__ aj,
        const float* __restrict__ ai, const unsigned short* __restrict__ h1b,
        float* __restrict__ out) {
    const int lane = threadIdx.x & 63;
    const int wid  = threadIdx.x >> 6;
    const int n = blockIdx.x * 4 + wid;
    if (n >= NNODES) return;

    const int start = rowstart[n];
    const int end   = rowstart[n + 1];
    const float ain = ai[n];

    const int  cg   = lane & 7;
    const int  sg   = lane >> 3;
    const bool chOK = (cg < 5);         // 40 channels = 5 uint4 chunks
    float4 accA = make_float4(0.f, 0.f, 0.f, 0.f);
    float4 accB = make_float4(0.f, 0.f, 0.f, 0.f);
    float  esum = 0.0f;

    for (int c = start; c < end; c += 64) {
        int rem = end - c;
        int cnt = (rem < 64) ? rem : 64;
        int   s   = 0;
        float ajv = 0.0f;
        if (lane < cnt) {
            s   = csr_src[c + lane];
            ajv = aj[s];
        }
        int sj0 = __shfl(s, 0 * 8 + sg, 64);
        int sj1 = __shfl(s, 1 * 8 + sg, 64);
        int sj2 = __shfl(s, 2 * 8 + sg, 64);
        int sj3 = __shfl(s, 3 * 8 + sg, 64);
        int sj4 = __shfl(s, 4 * 8 + sg, 64);
        int sj5 = __shfl(s, 5 * 8 + sg, 64);
        int sj6 = __shfl(s, 6 * 8 + sg, 64);
        int sj7 = __shfl(s, 7 * 8 + sg, 64);
        uint4 h0v, h1v, h2v, h3v, h4v, h5v, h6v, h7v;
#define GATH(T, SJ, HV) \
        if (chOK && (T) * 8 + sg < cnt) \
            HV = *(const uint4*)&h1b[(unsigned)((SJ) * 40) + (cg << 3)];
        GATH(0, sj0, h0v) GATH(1, sj1, h1v) GATH(2, sj2, h2v) GATH(3, sj3, h3v)
        GATH(4, sj4, h4v) GATH(5, sj5, h5v) GATH(6, sj6, h6v) GATH(7, sj7, h7v)
#undef GATH
        float tv = ain + ajv;
        tv = (tv > 0.0f) ? tv : 0.2f * tv;
        float av = (lane < cnt) ? __expf(tv) : 0.0f;
        esum += av;                                 // each edge exactly once
#define USE(T, HV) \
        { float a = __shfl(av, (T) * 8 + sg, 64); \
          if (chOK && (T) * 8 + sg < cnt) { \
            accA.x = fmaf(a, __uint_as_float(HV.x << 16),          accA.x); \
            accA.y = fmaf(a, __uint_as_float(HV.x & 0xFFFF0000u),  accA.y); \
            accA.z = fmaf(a, __uint_as_float(HV.y << 16),          accA.z); \
            accA.w = fmaf(a, __uint_as_float(HV.y & 0xFFFF0000u),  accA.w); \
            accB.x = fmaf(a, __uint_as_float(HV.z << 16),          accB.x); \
            accB.y = fmaf(a, __uint_as_float(HV.z & 0xFFFF0000u),  accB.y); \
            accB.z = fmaf(a, __uint_as_float(HV.w << 16),          accB.z); \
            accB.w = fmaf(a, __uint_as_float(HV.w & 0xFFFF0000u),  accB.w); \
          } }
        USE(0, h0v) USE(1, h1v) USE(2, h2v) USE(3, h3v)
        USE(4, h4v) USE(5, h5v) USE(6, h6v) USE(7, h7v)
#undef USE
    }
#pragma unroll
    for (int off = 32; off > 0; off >>= 1) esum += __shfl_xor(esum, off, 64);
    const float inv = 1.0f / esum;
#pragma unroll
    for (int off = 8; off < 64; off <<= 1) {
        accA.x += __shfl_xor(accA.x, off, 64);
        accA.y += __shfl_xor(accA.y, off, 64);
        accA.z += __shfl_xor(accA.z, off, 64);
        accA.w += __shfl_xor(accA.w, off, 64);
        accB.x += __shfl_xor(accB.x, off, 64);
        accB.y += __shfl_xor(accB.y, off, 64);
        accB.z += __shfl_xor(accB.z, off, 64);
        accB.w += __shfl_xor(accB.w, off, 64);
    }
    accA.x *= inv; accA.y *= inv; accA.z *= inv; accA.w *= inv;
    accB.x *= inv; accB.y *= inv; accB.z *= inv; accB.w *= inv;

    // log_softmax over 40 values (5 uint4 chunks in lanes cg<5; values
    // replicated across all 8 sg groups after the xor-reduce)
    float mx = -INFINITY;
    if (chOK) {
        mx = fmaxf(fmaxf(fmaxf(accA.x, accA.y), fmaxf(accA.z, accA.w)),
                   fmaxf(fmaxf(accB.x, accB.y), fmaxf(accB.z, accB.w)));
    }
#pragma unroll
    for (int off = 1; off < 8; off <<= 1) mx = fmaxf(mx, __shfl_xor(mx, off, 64));
    float sm = 0.0f;
    if (chOK) {
        sm = __expf(accA.x - mx) + __expf(accA.y - mx) +
             __expf(accA.z - mx) + __expf(accA.w - mx) +
             __expf(accB.x - mx) + __expf(accB.y - mx) +
             __expf(accB.z - mx) + __expf(accB.w - mx);
    }
#pragma unroll
    for (int off = 1; off < 8; off <<= 1) sm += __shfl_xor(sm, off, 64);
    float ls = mx + logf(sm);
    if (sg == 0 && chOK) {
        float4 oA = make_float4(accA.x - ls, accA.y - ls, accA.z - ls, accA.w - ls);
        float4 oB = make_float4(accB.x - ls, accB.y - ls, accB.z - ls, accB.w - ls);
        *(float4*)&out[(size_t)n * 40 + (cg << 3)]     = oA;
        *(float4*)&out[(size_t)n * 40 + (cg << 3) + 4] = oB;
    }
}

// ===========================================================================
extern "C" void kernel_launch(void* const* d_in, const int* in_sizes, int n_in,
                              void* d_out, int out_size, void* d_ws, size_t ws_size,
                              hipStream_t stream) {
    const float* x    = (const float*)d_in[0];
    const int*   ei   = (const int*)  d_in[1];
    const float* W0   = (const float*)d_in[2];
    const float* att0 = (const float*)d_in[3];
    const float* W1   = (const float*)d_in[4];
    const float* att1 = (const float*)d_in[5];
    float* out = (float*)d_out;

    // workspace layout (16B-aligned segments)
    int* wi = (int*)d_ws;
    int*  cnt      = wi;                        // 100352
    int*  bstart   = cnt + 100352;              // 1024
    int*  rowstart = bstart + 1024;             // 100352
    unsigned int* stage = (unsigned int*)(rowstart + 100352);     // KBUCK*NSUB*CAPS
    int*  csr_src  = (int*)(stage + (size_t)KBUCK * NSUB * CAPS); // 1,700,096
    unsigned short* h0b = (unsigned short*)(csr_src + 1700096);   // N*64 bf16 (12.8MB)
    unsigned short* h1b = h0b + (size_t)NNODES * 64;              // N*40 bf16 (8MB)
    float* fbase = (float*)(h1b + (size_t)NNODES * 40);           // -> 16B aligned
    float* ai0 = fbase;
    float* aj0 = ai0 + 100352;
    float* ai1 = aj0 + 100352;
    float* aj1 = ai1 + 100352;

    const int B = 256;
    const int aggGrid = (NNODES + 3) / 4;
    const int fusedGrid = (GGRP + BGRP) * 8;

    // ---- CSR build (bucket half) fused with layer-0 GEMM (independent) ----
    zero_cnt<<<(KBUCK * NSUB * CPAD + B - 1) / B, B, 0, stream>>>(cnt);
    fusedA<<<fusedGrid, B, 0, stream>>>(ei, cnt, stage, x, W0, att0, h0b, ai0, aj0);
    bucket_scan<<<1, 1024, 0, stream>>>(cnt, bstart);
    bucket_scatter<<<KBUCK, B, 0, stream>>>(cnt, bstart, stage, rowstart, csr_src);

    // ---- layer-0 aggregation + fused gemm1 + layer-1 attention scalars ----
    agg_gemm1<<<aggGrid, B, 0, stream>>>(rowstart, csr_src, aj0, ai0, h0b,
                                         W1, att1, h1b, ai1, aj1);

    // ---- layer-1 aggregation + log_softmax ----
    agg_lsm<<<aggGrid, B, 0, stream>>>(rowstart, csr_src, aj1, ai1, h1b, out);
}

// Round 10
// 375.780 us; speedup vs baseline: 1.0705x; 1.0649x over previous
//
#include <hip/hip_runtime.h>
#include <math.h>

#define NNODES 100000
#define NEDGES 1600000
#define ETOT   (NEDGES + NNODES)   // self-loops appended

// bucket-major CSR build
#define BSZ   128                         // dst nodes per bucket (dst >> 7)
#define KBUCK ((NNODES + BSZ - 1) / BSZ)  // 782 buckets
#define CAP   2816                        // max TOTAL entries per bucket
#define NSUB  8                           // per-XCD sub-buckets
#define CAPS  768                         // per sub-bucket
#define CPAD  16                          // counter padding (one per 64B line)

#define GEMMB 1563                        // gemm0 blocks (64 nodes each)
#define EPT   4                           // edges per thread in bucket half
#define BUCKB ((ETOT + 1024 - 1) / 1024)  // 1661 bucket blocks
#define GGRP  ((GEMMB + 7) / 8)           // 196 gemm groups-of-8
#define BGRP  ((BUCKB + 7) / 8)           // 208 bucket groups-of-8

__device__ __forceinline__ int xcc_id() {
    int x;
    asm volatile("s_getreg_b32 %0, hwreg(HW_REG_XCC_ID)" : "=s"(x));
    return x & (NSUB - 1);
}

// fp32 -> bf16 with round-to-nearest-even (bit-level, no NaN inputs here)
__device__ __forceinline__ unsigned short f2bf(float f) {
    unsigned u = __float_as_uint(f);
    return (unsigned short)((u + 0x7FFFu + ((u >> 16) & 1u)) >> 16);
}

// ===========================================================================
__global__ void zero_cnt(int* __restrict__ cnt) {
    int i = blockIdx.x * blockDim.x + threadIdx.x;
    if (i < KBUCK * NSUB * CPAD) cnt[i] = 0;
}

// ---------------------------------------------------------------------------
// bucket half: append (dst-low, src) to XCD-local sub-bucket. 4-edge ILP.
__device__ __forceinline__ void bucket_body(int bb, const int* __restrict__ ei,
                                            int* __restrict__ cnt,
                                            unsigned int* __restrict__ stage) {
    const int t = threadIdx.x;
    const int xg = xcc_id();
#pragma unroll
    for (int r = 0; r < EPT; ++r) {
        int e = bb * 1024 + r * 256 + t;
        if (e < ETOT) {
            int src, dst;
            if (e < NEDGES) { src = ei[e]; dst = ei[NEDGES + e]; }
            else            { src = dst = e - NEDGES; }
            int sb = (dst >> 7) * NSUB + xg;
            int pos = atomicAdd(&cnt[sb * CPAD], 1);
            if (pos < CAPS)
                stage[(size_t)sb * CAPS + pos] =
                    ((unsigned)(dst & 127) << 24) | (unsigned)src;
        }
    }
}

// ---------------------------------------------------------------------------
// gemm half: h0 = x @ W0.T (64 out-ch, stored bf16) + attention scalars.
// Full-K LDS staging + 3-deep x register prefetch pipeline.
__device__ __forceinline__ void gemm0_body(int gb, const float* __restrict__ x,
                                           const float* __restrict__ W,
                                           const float* __restrict__ att,
                                           unsigned short* __restrict__ h0b,
                                           float* __restrict__ ai,
                                           float* __restrict__ aj) {
    __shared__ float Wt[128 * 68];
    const int tid = threadIdx.x;
    const int nb = gb * 64;

    const int lane = tid & 63;
    const int w    = tid >> 6;
    const int ocg  = lane & 15;          // owns out-ch ocg*4 .. ocg*4+3
    const int ng   = lane >> 4;
    const int nodeLocal = w * 16 + ng * 4;

    const float* xp[4];
#pragma unroll
    for (int j = 0; j < 4; ++j) {
        int node = nb + nodeLocal + j;
        xp[j] = x + (size_t)(node < NNODES ? node : NNODES - 1) * 128;
    }

    // x pipeline issued BEFORE W staging (overlaps stage + barrier)
    float4 xa[4], xb[4], xc[4];
#pragma unroll
    for (int j = 0; j < 4; ++j) {
        xa[j] = *(const float4*)(xp[j] + 0);
        xb[j] = *(const float4*)(xp[j] + 4);
        xc[j] = *(const float4*)(xp[j] + 8);
    }

    for (int i = tid; i < 128 * 64; i += 256) {
        int oc = i >> 7, k = i & 127;
        Wt[k * 68 + oc] = W[i];
    }
    __syncthreads();

    float4 acc[4];
#pragma unroll
    for (int j = 0; j < 4; ++j) acc[j] = make_float4(0.f, 0.f, 0.f, 0.f);

#pragma unroll 4
    for (int k4 = 0; k4 < 32; ++k4) {
        const int kb = k4 * 4;
        int kpf = kb + 12; if (kpf > 124) kpf = 124;
        float4 xn0 = *(const float4*)(xp[0] + kpf);
        float4 xn1 = *(const float4*)(xp[1] + kpf);
        float4 xn2 = *(const float4*)(xp[2] + kpf);
        float4 xn3 = *(const float4*)(xp[3] + kpf);
        float4 wv0 = *(const float4*)&Wt[(kb + 0) * 68 + ocg * 4];
        float4 wv1 = *(const float4*)&Wt[(kb + 1) * 68 + ocg * 4];
        float4 wv2 = *(const float4*)&Wt[(kb + 2) * 68 + ocg * 4];
        float4 wv3 = *(const float4*)&Wt[(kb + 3) * 68 + ocg * 4];
#pragma unroll
        for (int j = 0; j < 4; ++j) {
            float4 xv = xa[j];
            acc[j].x += xv.x * wv0.x + xv.y * wv1.x + xv.z * wv2.x + xv.w * wv3.x;
            acc[j].y += xv.x * wv0.y + xv.y * wv1.y + xv.z * wv2.y + xv.w * wv3.y;
            acc[j].z += xv.x * wv0.z + xv.y * wv1.z + xv.z * wv2.z + xv.w * wv3.z;
            acc[j].w += xv.x * wv0.w + xv.y * wv1.w + xv.z * wv2.w + xv.w * wv3.w;
        }
        xa[0] = xb[0]; xa[1] = xb[1]; xa[2] = xb[2]; xa[3] = xb[3];
        xb[0] = xc[0]; xb[1] = xc[1]; xb[2] = xc[2]; xb[3] = xc[3];
        xc[0] = xn0;   xc[1] = xn1;   xc[2] = xn2;   xc[3] = xn3;
    }

    const int ocb = ocg * 4;
    float ati[4], atj[4];
#pragma unroll
    for (int i = 0; i < 4; ++i) {
        ati[i] = att[ocb + i];
        atj[i] = att[64 + ocb + i];
    }

#pragma unroll
    for (int j = 0; j < 4; ++j) {
        int nodeG = nb + nodeLocal + j;
        float pai = acc[j].x * ati[0] + acc[j].y * ati[1] + acc[j].z * ati[2] + acc[j].w * ati[3];
        float paj = acc[j].x * atj[0] + acc[j].y * atj[1] + acc[j].z * atj[2] + acc[j].w * atj[3];
#pragma unroll
        for (int off = 1; off < 16; off <<= 1) {
            pai += __shfl_xor(pai, off, 64);
            paj += __shfl_xor(paj, off, 64);
        }
        if (nodeG < NNODES) {
            unsigned p0 = ((unsigned)f2bf(acc[j].y) << 16) | f2bf(acc[j].x);
            unsigned p1 = ((unsigned)f2bf(acc[j].w) << 16) | f2bf(acc[j].z);
            *(uint2*)&h0b[(size_t)nodeG * 64 + ocb] = make_uint2(p0, p1);
            if (ocg == 0) { ai[nodeG] = pai; aj[nodeG] = paj; }
        }
    }
}

// ---------------------------------------------------------------------------
// Fused heterogeneous kernel (bucket ∥ gemm0; overlap is real, R4 lesson)
__global__ __launch_bounds__(256) void fusedA(
        const int* __restrict__ ei, int* __restrict__ cnt,
        unsigned int* __restrict__ stage,
        const float* __restrict__ x, const float* __restrict__ W0,
        const float* __restrict__ att0,
        unsigned short* __restrict__ h0b, float* __restrict__ ai0,
        float* __restrict__ aj0) {
    const int bid = blockIdx.x;
    const int grp = bid >> 3, sub = bid & 7;
    if ((grp & 1) && (grp >> 1) < GGRP) {
        int g = (grp >> 1) * 8 + sub;
        if (g < GEMMB) gemm0_body(g, x, W0, att0, h0b, ai0, aj0);
    } else {
        int bg = grp - min(GGRP, (grp + 1) >> 1);
        int bb = bg * 8 + sub;
        if (bb < BUCKB) bucket_body(bb, ei, cnt, stage);
    }
}

// ===========================================================================
__global__ void bucket_scan(const int* __restrict__ cnt, int* __restrict__ bstart) {
    __shared__ int wsum[16];
    const int t = threadIdx.x;                      // 1024 threads
    int x = 0;
    if (t < KBUCK) {
#pragma unroll
        for (int s = 0; s < NSUB; ++s) x += min(cnt[(t * NSUB + s) * CPAD], CAPS);
    }
    int lane = t & 63, w = t >> 6;
    int inc = x;
#pragma unroll
    for (int off = 1; off < 64; off <<= 1) {
        int u = __shfl_up(inc, off, 64);
        if (lane >= off) inc += u;
    }
    if (lane == 63) wsum[w] = inc;
    __syncthreads();
    if (t == 0) {
        int s = 0;
#pragma unroll
        for (int j = 0; j < 16; ++j) { int y = wsum[j]; wsum[j] = s; s += y; }
    }
    __syncthreads();
    int excl = inc - x + wsum[w];
    if (t < KBUCK) bstart[t] = excl;
    if (t == KBUCK) bstart[KBUCK] = excl;
}

__global__ __launch_bounds__(256) void bucket_scatter(
        const int* __restrict__ cnt, const int* __restrict__ bstart,
        const unsigned int* __restrict__ stage, int* __restrict__ rowstart,
        int* __restrict__ csr_src) {
    __shared__ unsigned int ent[CAP];
    __shared__ int hist[BSZ];
    __shared__ int scnt[NSUB];
    __shared__ int soff[NSUB + 1];
    __shared__ int wtot;
    const int b = blockIdx.x, t = threadIdx.x;
    const int n0 = b * BSZ;
    const int base = bstart[b];

    if (t < BSZ) hist[t] = 0;
    if (t < NSUB) scnt[t] = min(cnt[(b * NSUB + t) * CPAD], CAPS);
    __syncthreads();
    if (t == 0) {
        int s = 0;
#pragma unroll
        for (int x = 0; x < NSUB; ++x) { soff[x] = s; s += scnt[x]; }
        soff[NSUB] = s;
    }
    __syncthreads();

#pragma unroll
    for (int x = 0; x < NSUB; ++x) {
        const int cx = scnt[x];
        const int ox = soff[x];
        const unsigned int* sp = stage + (size_t)(b * NSUB + x) * CAPS;
        for (int i = t; i < cx; i += 256) {
            unsigned int v = sp[i];
            ent[ox + i] = v;
            atomicAdd(&hist[v >> 24], 1);
        }
    }
    __syncthreads();
    const int c = soff[NSUB];

    int lane = t & 63, w = t >> 6;
    int v = (t < BSZ) ? hist[t] : 0;
    int inc = v;
#pragma unroll
    for (int off = 1; off < 64; off <<= 1) {
        int u = __shfl_up(inc, off, 64);
        if (lane >= off) inc += u;
    }
    if (t == 63) wtot = inc;
    __syncthreads();
    int excl = inc - v + ((w == 1) ? wtot : 0);
    if (t < BSZ) {
        int node = n0 + t;
        if (node <= NNODES) rowstart[node] = base + excl;
    }
    __syncthreads();
    if (t < BSZ) hist[t] = excl;
    __syncthreads();
    for (int i = t; i < c; i += 256) {
        unsigned int e = ent[i];
        int pos = atomicAdd(&hist[e >> 24], 1);
        csr_src[base + pos] = (int)(e & 0xFFFFFFu);
    }
}

// ===========================================================================
// Layer-0 aggregation + fused gemm1 -> bf16 h1 + layer-1 attention scalars.
// R10: R5 trip structure (1 gather/trip — R9's 8-deep batch cost occupancy
// and regressed) + own-edge alpha in the coalesced preamble (1 aj-gather +
// 1 expf per edge instead of 8x redundant), broadcast via FULL-WAVE shfl
// (R8-verified semantics: ds_bpermute sources must be EXEC-active).
// ===========================================================================
__global__ __launch_bounds__(256) void agg_gemm1(
        const int* __restrict__ rowstart, const int* __restrict__ csr_src,
        const float* __restrict__ aj,
        const float* __restrict__ ai, const unsigned short* __restrict__ h0b,
        const float* __restrict__ W1, const float* __restrict__ att1,
        unsigned short* __restrict__ h1b, float* __restrict__ ai1,
        float* __restrict__ aj1) {
    __shared__ float  W1L[64 * 68];     // oc-major, stride 68 (2-way banks: free)
    __shared__ float  rowbuf[4][64];    // per-wave combined row

    const int tid = threadIdx.x;
    for (int i = tid; i < 64 * 64; i += 256) {
        int oc = i >> 6, k = i & 63;
        W1L[oc * 68 + k] = (oc < 40) ? W1[oc * 64 + k] : 0.0f;
    }
    __syncthreads();

    const int lane = tid & 63;
    const int wid  = tid >> 6;
    const int n = blockIdx.x * 4 + wid;
    if (n >= NNODES) return;

    const int start = rowstart[n];
    const int end   = rowstart[n + 1];
    const float ain = ai[n];

    const int cg = lane & 7;            // 8 channel-groups of 8 ch
    const int sg = lane >> 3;           // 8 edge slots
    const int cgo = cg << 3;            // channel offset
    float4 accA = make_float4(0.f, 0.f, 0.f, 0.f);
    float4 accB = make_float4(0.f, 0.f, 0.f, 0.f);
    float  esum = 0.0f;

    for (int c = start; c < end; c += 64) {
        int rem = end - c;
        int cnt = (rem < 64) ? rem : 64;            // wave-uniform
        int   s   = 0;
        float ajv = 0.0f;
        if (lane < cnt) {
            s   = csr_src[c + lane];
            ajv = aj[s];                            // own-edge gather, once
        }
        float tv = ain + ajv;
        tv = (tv > 0.0f) ? tv : 0.2f * tv;
        float av = (lane < cnt) ? __expf(tv) : 0.0f;
        esum += av;                                 // each edge exactly once
        for (int j0 = 0; j0 < cnt; j0 += 8) {       // uniform trips
            int j  = j0 + sg;
            int   sj = __shfl(s,  j, 64);           // full-wave shfl
            float a  = __shfl(av, j, 64);           // full-wave shfl
            if (j < cnt) {
                uint4 hv = *(const uint4*)&h0b[(unsigned)(sj << 6) + cgo];
                accA.x = fmaf(a, __uint_as_float(hv.x << 16),         accA.x);
                accA.y = fmaf(a, __uint_as_float(hv.x & 0xFFFF0000u), accA.y);
                accA.z = fmaf(a, __uint_as_float(hv.y << 16),         accA.z);
                accA.w = fmaf(a, __uint_as_float(hv.y & 0xFFFF0000u), accA.w);
                accB.x = fmaf(a, __uint_as_float(hv.z << 16),         accB.x);
                accB.y = fmaf(a, __uint_as_float(hv.z & 0xFFFF0000u), accB.y);
                accB.z = fmaf(a, __uint_as_float(hv.w << 16),         accB.z);
                accB.w = fmaf(a, __uint_as_float(hv.w & 0xFFFF0000u), accB.w);
            }
        }
    }
#pragma unroll
    for (int off = 32; off > 0; off >>= 1) esum += __shfl_xor(esum, off, 64);
    const float inv = 1.0f / esum;
#pragma unroll
    for (int off = 8; off < 64; off <<= 1) {        // reduce over 8 edge slots
        accA.x += __shfl_xor(accA.x, off, 64);
        accA.y += __shfl_xor(accA.y, off, 64);
        accA.z += __shfl_xor(accA.z, off, 64);
        accA.w += __shfl_xor(accA.w, off, 64);
        accB.x += __shfl_xor(accB.x, off, 64);
        accB.y += __shfl_xor(accB.y, off, 64);
        accB.z += __shfl_xor(accB.z, off, 64);
        accB.w += __shfl_xor(accB.w, off, 64);
    }
    // normalize + relu, park row in LDS
    if (sg == 0) {
        float4 rA, rB;
        rA.x = fmaxf(accA.x * inv, 0.0f);
        rA.y = fmaxf(accA.y * inv, 0.0f);
        rA.z = fmaxf(accA.z * inv, 0.0f);
        rA.w = fmaxf(accA.w * inv, 0.0f);
        rB.x = fmaxf(accB.x * inv, 0.0f);
        rB.y = fmaxf(accB.y * inv, 0.0f);
        rB.z = fmaxf(accB.z * inv, 0.0f);
        rB.w = fmaxf(accB.w * inv, 0.0f);
        *(float4*)&rowbuf[wid][cgo]     = rA;
        *(float4*)&rowbuf[wid][cgo + 4] = rB;
    }

    // ---- fused gemm1: h1[n,oc] = sum_k row[k] * W1[oc,k] ----
    const int oc = lane;                 // lanes 40..63 hit zero-padded W1 rows
    float hacc = 0.0f;
#pragma unroll
    for (int k4 = 0; k4 < 16; ++k4) {
        float4 rv = *(const float4*)&rowbuf[wid][k4 * 4];       // broadcast
        float4 wv = *(const float4*)&W1L[oc * 68 + k4 * 4];
        hacc = fmaf(rv.x, wv.x, hacc);
        hacc = fmaf(rv.y, wv.y, hacc);
        hacc = fmaf(rv.z, wv.z, hacc);
        hacc = fmaf(rv.w, wv.w, hacc);
    }

    const bool ocOK = (oc < 40);
    if (ocOK) h1b[(size_t)n * 40 + oc] = f2bf(hacc);
    float pai = ocOK ? hacc * att1[oc]      : 0.0f;
    float paj = ocOK ? hacc * att1[40 + oc] : 0.0f;
#pragma unroll
    for (int off = 1; off < 64; off <<= 1) {
        pai += __shfl_xor(pai, off, 64);
        paj += __shfl_xor(paj, off, 64);
    }
    if (lane == 0) { ai1[n] = pai; aj1[n] = paj; }
}

// ===========================================================================
// Layer-1 aggregation (bf16 h1, 40 ch) + log_softmax. R10: same own-edge
// alpha preamble + R5 trip structure.
// ===========================================================================
__global__ __launch_bounds__(256) void agg_lsm(
        const int* __restrict__ rowstart, const int* __restrict__ csr_src,
        const float* __restrict__ aj,
        const float* __restrict__ ai, const unsigned short* __restrict__ h1b,
        float* __restrict__ out) {
    const int lane = threadIdx.x & 63;
    const int wid  = threadIdx.x >> 6;
    const int n = blockIdx.x * 4 + wid;
    if (n >= NNODES) return;

    const int start = rowstart[n];
    const int end   = rowstart[n + 1];
    const float ain = ai[n];

    const int  cg   = lane & 7;
    const int  sg   = lane >> 3;
    const bool chOK = (cg < 5);         // 40 channels = 5 uint4 chunks
    float4 accA = make_float4(0.f, 0.f, 0.f, 0.f);
    float4 accB = make_float4(0.f, 0.f, 0.f, 0.f);
    float  esum = 0.0f;

    for (int c = start; c < end; c += 64) {
        int rem = end - c;
        int cnt = (rem < 64) ? rem : 64;
        int   s   = 0;
        float ajv = 0.0f;
        if (lane < cnt) {
            s   = csr_src[c + lane];
            ajv = aj[s];
        }
        float tv = ain + ajv;
        tv = (tv > 0.0f) ? tv : 0.2f * tv;
        float av = (lane < cnt) ? __expf(tv) : 0.0f;
        esum += av;                                 // each edge exactly once
        for (int j0 = 0; j0 < cnt; j0 += 8) {
            int j  = j0 + sg;
            int   sj = __shfl(s,  j, 64);           // full-wave shfl
            float a  = __shfl(av, j, 64);           // full-wave shfl
            if (chOK && j < cnt) {
                uint4 hv = *(const uint4*)&h1b[(unsigned)(sj * 40) + (cg << 3)];
                accA.x = fmaf(a, __uint_as_float(hv.x << 16),         accA.x);
                accA.y = fmaf(a, __uint_as_float(hv.x & 0xFFFF0000u), accA.y);
                accA.z = fmaf(a, __uint_as_float(hv.y << 16),         accA.z);
                accA.w = fmaf(a, __uint_as_float(hv.y & 0xFFFF0000u), accA.w);
                accB.x = fmaf(a, __uint_as_float(hv.z << 16),         accB.x);
                accB.y = fmaf(a, __uint_as_float(hv.z & 0xFFFF0000u), accB.y);
                accB.z = fmaf(a, __uint_as_float(hv.w << 16),         accB.z);
                accB.w = fmaf(a, __uint_as_float(hv.w & 0xFFFF0000u), accB.w);
            }
        }
    }
#pragma unroll
    for (int off = 32; off > 0; off >>= 1) esum += __shfl_xor(esum, off, 64);
    const float inv = 1.0f / esum;
#pragma unroll
    for (int off = 8; off < 64; off <<= 1) {
        accA.x += __shfl_xor(accA.x, off, 64);
        accA.y += __shfl_xor(accA.y, off, 64);
        accA.z += __shfl_xor(accA.z, off, 64);
        accA.w += __shfl_xor(accA.w, off, 64);
        accB.x += __shfl_xor(accB.x, off, 64);
        accB.y += __shfl_xor(accB.y, off, 64);
        accB.z += __shfl_xor(accB.z, off, 64);
        accB.w += __shfl_xor(accB.w, off, 64);
    }
    accA.x *= inv; accA.y *= inv; accA.z *= inv; accA.w *= inv;
    accB.x *= inv; accB.y *= inv; accB.z *= inv; accB.w *= inv;

    // log_softmax over 40 values (5 uint4 chunks in lanes cg<5; values
    // replicated across all 8 sg groups after the xor-reduce)
    float mx = -INFINITY;
    if (chOK) {
        mx = fmaxf(fmaxf(fmaxf(accA.x, accA.y), fmaxf(accA.z, accA.w)),
                   fmaxf(fmaxf(accB.x, accB.y), fmaxf(accB.z, accB.w)));
    }
#pragma unroll
    for (int off = 1; off < 8; off <<= 1) mx = fmaxf(mx, __shfl_xor(mx, off, 64));
    float sm = 0.0f;
    if (chOK) {
        sm = __expf(accA.x - mx) + __expf(accA.y - mx) +
             __expf(accA.z - mx) + __expf(accA.w - mx) +
             __expf(accB.x - mx) + __expf(accB.y - mx) +
             __expf(accB.z - mx) + __expf(accB.w - mx);
    }
#pragma unroll
    for (int off = 1; off < 8; off <<= 1) sm += __shfl_xor(sm, off, 64);
    float ls = mx + logf(sm);
    if (sg == 0 && chOK) {
        float4 oA = make_float4(accA.x - ls, accA.y - ls, accA.z - ls, accA.w - ls);
        float4 oB = make_float4(accB.x - ls, accB.y - ls, accB.z - ls, accB.w - ls);
        *(float4*)&out[(size_t)n * 40 + (cg << 3)]     = oA;
        *(float4*)&out[(size_t)n * 40 + (cg << 3) + 4] = oB;
    }
}

// ===========================================================================
extern "C" void kernel_launch(void* const* d_in, const int* in_sizes, int n_in,
                              void* d_out, int out_size, void* d_ws, size_t ws_size,
                              hipStream_t stream) {
    const float* x    = (const float*)d_in[0];
    const int*   ei   = (const int*)  d_in[1];
    const float* W0   = (const float*)d_in[2];
    const float* att0 = (const float*)d_in[3];
    const float* W1   = (const float*)d_in[4];
    const float* att1 = (const float*)d_in[5];
    float* out = (float*)d_out;

    // workspace layout (16B-aligned segments)
    int* wi = (int*)d_ws;
    int*  cnt      = wi;                        // 100352
    int*  bstart   = cnt + 100352;              // 1024
    int*  rowstart = bstart + 1024;             // 100352
    unsigned int* stage = (unsigned int*)(rowstart + 100352);     // KBUCK*NSUB*CAPS
    int*  csr_src  = (int*)(stage + (size_t)KBUCK * NSUB * CAPS); // 1,700,096
    unsigned short* h0b = (unsigned short*)(csr_src + 1700096);   // N*64 bf16 (12.8MB)
    unsigned short* h1b = h0b + (size_t)NNODES * 64;              // N*40 bf16 (8MB)
    float* fbase = (float*)(h1b + (size_t)NNODES * 40);           // -> 16B aligned
    float* ai0 = fbase;
    float* aj0 = ai0 + 100352;
    float* ai1 = aj0 + 100352;
    float* aj1 = ai1 + 100352;

    const int B = 256;
    const int aggGrid = (NNODES + 3) / 4;
    const int fusedGrid = (GGRP + BGRP) * 8;

    // ---- CSR build (bucket half) fused with layer-0 GEMM (independent) ----
    zero_cnt<<<(KBUCK * NSUB * CPAD + B - 1) / B, B, 0, stream>>>(cnt);
    fusedA<<<fusedGrid, B, 0, stream>>>(ei, cnt, stage, x, W0, att0, h0b, ai0, aj0);
    bucket_scan<<<1, 1024, 0, stream>>>(cnt, bstart);
    bucket_scatter<<<KBUCK, B, 0, stream>>>(cnt, bstart, stage, rowstart, csr_src);

    // ---- layer-0 aggregation + fused gemm1 + layer-1 attention scalars ----
    agg_gemm1<<<aggGrid, B, 0, stream>>>(rowstart, csr_src, aj0, ai0, h0b,
                                         W1, att1, h1b, ai1, aj1);

    // ---- layer-1 aggregation + log_softmax ----
    agg_lsm<<<aggGrid, B, 0, stream>>>(rowstart, csr_src, aj1, ai1, h1b, out);
}

// Round 11
// 373.470 us; speedup vs baseline: 1.0771x; 1.0062x over previous
//
#include <hip/hip_runtime.h>
#include <math.h>

#define NNODES 100000
#define NEDGES 1600000
#define ETOT   (NEDGES + NNODES)   // self-loops appended

// bucket-major CSR build
#define BSZ   128                         // dst nodes per bucket (dst >> 7)
#define KBUCK ((NNODES + BSZ - 1) / BSZ)  // 782 buckets
#define CAP   2816                        // max TOTAL entries per bucket
#define NSUB  8                           // per-XCD sub-buckets
#define CAPS  768                         // per sub-bucket
#define CPAD  16                          // counter padding (one per 64B line)

#define GEMMB 1563                        // gemm0 blocks (64 nodes each)
#define EPT   4                           // edges per thread in bucket half
#define BUCKB ((ETOT + 1024 - 1) / 1024)  // 1661 bucket blocks
#define GGRP  ((GEMMB + 7) / 8)           // 196 gemm groups-of-8
#define BGRP  ((BUCKB + 7) / 8)           // 208 bucket groups-of-8

__device__ __forceinline__ int xcc_id() {
    int x;
    asm volatile("s_getreg_b32 %0, hwreg(HW_REG_XCC_ID)" : "=s"(x));
    return x & (NSUB - 1);
}

// fp32 -> bf16 with round-to-nearest-even (bit-level, no NaN inputs here)
__device__ __forceinline__ unsigned short f2bf(float f) {
    unsigned u = __float_as_uint(f);
    return (unsigned short)((u + 0x7FFFu + ((u >> 16) & 1u)) >> 16);
}

// ===========================================================================
__global__ void zero_cnt(int* __restrict__ cnt) {
    int i = blockIdx.x * blockDim.x + threadIdx.x;
    if (i < KBUCK * NSUB * CPAD) cnt[i] = 0;
}

// ---------------------------------------------------------------------------
// bucket half: append (dst-low, src) to XCD-local sub-bucket. 4-edge ILP.
__device__ __forceinline__ void bucket_body(int bb, const int* __restrict__ ei,
                                            int* __restrict__ cnt,
                                            unsigned int* __restrict__ stage) {
    const int t = threadIdx.x;
    const int xg = xcc_id();
#pragma unroll
    for (int r = 0; r < EPT; ++r) {
        int e = bb * 1024 + r * 256 + t;
        if (e < ETOT) {
            int src, dst;
            if (e < NEDGES) { src = ei[e]; dst = ei[NEDGES + e]; }
            else            { src = dst = e - NEDGES; }
            int sb = (dst >> 7) * NSUB + xg;
            int pos = atomicAdd(&cnt[sb * CPAD], 1);
            if (pos < CAPS)
                stage[(size_t)sb * CAPS + pos] =
                    ((unsigned)(dst & 127) << 24) | (unsigned)src;
        }
    }
}

// ---------------------------------------------------------------------------
// gemm half: h0 = x @ W0.T. R11: h0 stored INT8 row-quantized (64B/node +
// per-node scale) — halves the agg-gather table 12.8->6.4MB to raise L2 hit
// rate (R9 showed per-CU miss capacity is the agg wall; fewer bytes/misses
// is the one untried mechanism). ai/aj attention scalars stay fp32-exact.
__device__ __forceinline__ void gemm0_body(int gb, const float* __restrict__ x,
                                           const float* __restrict__ W,
                                           const float* __restrict__ att,
                                           unsigned int* __restrict__ h0q,
                                           float* __restrict__ scl,
                                           float* __restrict__ ai,
                                           float* __restrict__ aj) {
    __shared__ float Wt[128 * 68];
    const int tid = threadIdx.x;
    const int nb = gb * 64;

    const int lane = tid & 63;
    const int w    = tid >> 6;
    const int ocg  = lane & 15;          // owns out-ch ocg*4 .. ocg*4+3
    const int ng   = lane >> 4;
    const int nodeLocal = w * 16 + ng * 4;

    const float* xp[4];
#pragma unroll
    for (int j = 0; j < 4; ++j) {
        int node = nb + nodeLocal + j;
        xp[j] = x + (size_t)(node < NNODES ? node : NNODES - 1) * 128;
    }

    // x pipeline issued BEFORE W staging (overlaps stage + barrier)
    float4 xa[4], xb[4], xc[4];
#pragma unroll
    for (int j = 0; j < 4; ++j) {
        xa[j] = *(const float4*)(xp[j] + 0);
        xb[j] = *(const float4*)(xp[j] + 4);
        xc[j] = *(const float4*)(xp[j] + 8);
    }

    for (int i = tid; i < 128 * 64; i += 256) {
        int oc = i >> 7, k = i & 127;
        Wt[k * 68 + oc] = W[i];
    }
    __syncthreads();

    float4 acc[4];
#pragma unroll
    for (int j = 0; j < 4; ++j) acc[j] = make_float4(0.f, 0.f, 0.f, 0.f);

#pragma unroll 4
    for (int k4 = 0; k4 < 32; ++k4) {
        const int kb = k4 * 4;
        int kpf = kb + 12; if (kpf > 124) kpf = 124;
        float4 xn0 = *(const float4*)(xp[0] + kpf);
        float4 xn1 = *(const float4*)(xp[1] + kpf);
        float4 xn2 = *(const float4*)(xp[2] + kpf);
        float4 xn3 = *(const float4*)(xp[3] + kpf);
        float4 wv0 = *(const float4*)&Wt[(kb + 0) * 68 + ocg * 4];
        float4 wv1 = *(const float4*)&Wt[(kb + 1) * 68 + ocg * 4];
        float4 wv2 = *(const float4*)&Wt[(kb + 2) * 68 + ocg * 4];
        float4 wv3 = *(const float4*)&Wt[(kb + 3) * 68 + ocg * 4];
#pragma unroll
        for (int j = 0; j < 4; ++j) {
            float4 xv = xa[j];
            acc[j].x += xv.x * wv0.x + xv.y * wv1.x + xv.z * wv2.x + xv.w * wv3.x;
            acc[j].y += xv.x * wv0.y + xv.y * wv1.y + xv.z * wv2.y + xv.w * wv3.y;
            acc[j].z += xv.x * wv0.z + xv.y * wv1.z + xv.z * wv2.z + xv.w * wv3.z;
            acc[j].w += xv.x * wv0.w + xv.y * wv1.w + xv.z * wv2.w + xv.w * wv3.w;
        }
        xa[0] = xb[0]; xa[1] = xb[1]; xa[2] = xb[2]; xa[3] = xb[3];
        xb[0] = xc[0]; xb[1] = xc[1]; xb[2] = xc[2]; xb[3] = xc[3];
        xc[0] = xn0;   xc[1] = xn1;   xc[2] = xn2;   xc[3] = xn3;
    }

    const int ocb = ocg * 4;
    float ati[4], atj[4];
#pragma unroll
    for (int i = 0; i < 4; ++i) {
        ati[i] = att[ocb + i];
        atj[i] = att[64 + ocb + i];
    }

#pragma unroll
    for (int j = 0; j < 4; ++j) {
        int nodeG = nb + nodeLocal + j;
        float pai = acc[j].x * ati[0] + acc[j].y * ati[1] + acc[j].z * ati[2] + acc[j].w * ati[3];
        float paj = acc[j].x * atj[0] + acc[j].y * atj[1] + acc[j].z * atj[2] + acc[j].w * atj[3];
#pragma unroll
        for (int off = 1; off < 16; off <<= 1) {
            pai += __shfl_xor(pai, off, 64);
            paj += __shfl_xor(paj, off, 64);
        }
        // per-node absmax over 64 ch (16 ocg lanes share node j)
        float m = fmaxf(fmaxf(fabsf(acc[j].x), fabsf(acc[j].y)),
                        fmaxf(fabsf(acc[j].z), fabsf(acc[j].w)));
#pragma unroll
        for (int off = 1; off < 16; off <<= 1) m = fmaxf(m, __shfl_xor(m, off, 64));
        float qs = (m > 0.0f) ? 127.0f / m : 0.0f;
        int b0 = (int)rintf(acc[j].x * qs);
        int b1 = (int)rintf(acc[j].y * qs);
        int b2 = (int)rintf(acc[j].z * qs);
        int b3 = (int)rintf(acc[j].w * qs);
        unsigned pack = (unsigned)(b0 & 0xFF) | ((unsigned)(b1 & 0xFF) << 8) |
                        ((unsigned)(b2 & 0xFF) << 16) | ((unsigned)(b3 & 0xFF) << 24);
        if (nodeG < NNODES) {
            h0q[(size_t)nodeG * 16 + ocg] = pack;   // 16 lanes x 4B = 64B row
            if (ocg == 0) {
                ai[nodeG]  = pai;
                aj[nodeG]  = paj;
                scl[nodeG] = m * (1.0f / 127.0f);
            }
        }
    }
}

// ---------------------------------------------------------------------------
// Fused heterogeneous kernel (bucket ∥ gemm0; overlap is real, R4 lesson)
__global__ __launch_bounds__(256) void fusedA(
        const int* __restrict__ ei, int* __restrict__ cnt,
        unsigned int* __restrict__ stage,
        const float* __restrict__ x, const float* __restrict__ W0,
        const float* __restrict__ att0,
        unsigned int* __restrict__ h0q, float* __restrict__ scl0,
        float* __restrict__ ai0, float* __restrict__ aj0) {
    const int bid = blockIdx.x;
    const int grp = bid >> 3, sub = bid & 7;
    if ((grp & 1) && (grp >> 1) < GGRP) {
        int g = (grp >> 1) * 8 + sub;
        if (g < GEMMB) gemm0_body(g, x, W0, att0, h0q, scl0, ai0, aj0);
    } else {
        int bg = grp - min(GGRP, (grp + 1) >> 1);
        int bb = bg * 8 + sub;
        if (bb < BUCKB) bucket_body(bb, ei, cnt, stage);
    }
}

// ===========================================================================
__global__ void bucket_scan(const int* __restrict__ cnt, int* __restrict__ bstart) {
    __shared__ int wsum[16];
    const int t = threadIdx.x;                      // 1024 threads
    int x = 0;
    if (t < KBUCK) {
#pragma unroll
        for (int s = 0; s < NSUB; ++s) x += min(cnt[(t * NSUB + s) * CPAD], CAPS);
    }
    int lane = t & 63, w = t >> 6;
    int inc = x;
#pragma unroll
    for (int off = 1; off < 64; off <<= 1) {
        int u = __shfl_up(inc, off, 64);
        if (lane >= off) inc += u;
    }
    if (lane == 63) wsum[w] = inc;
    __syncthreads();
    if (t == 0) {
        int s = 0;
#pragma unroll
        for (int j = 0; j < 16; ++j) { int y = wsum[j]; wsum[j] = s; s += y; }
    }
    __syncthreads();
    int excl = inc - x + wsum[w];
    if (t < KBUCK) bstart[t] = excl;
    if (t == KBUCK) bstart[KBUCK] = excl;
}

__global__ __launch_bounds__(256) void bucket_scatter(
        const int* __restrict__ cnt, const int* __restrict__ bstart,
        const unsigned int* __restrict__ stage, int* __restrict__ rowstart,
        int* __restrict__ csr_src) {
    __shared__ unsigned int ent[CAP];
    __shared__ int hist[BSZ];
    __shared__ int scnt[NSUB];
    __shared__ int soff[NSUB + 1];
    __shared__ int wtot;
    const int b = blockIdx.x, t = threadIdx.x;
    const int n0 = b * BSZ;
    const int base = bstart[b];

    if (t < BSZ) hist[t] = 0;
    if (t < NSUB) scnt[t] = min(cnt[(b * NSUB + t) * CPAD], CAPS);
    __syncthreads();
    if (t == 0) {
        int s = 0;
#pragma unroll
        for (int x = 0; x < NSUB; ++x) { soff[x] = s; s += scnt[x]; }
        soff[NSUB] = s;
    }
    __syncthreads();

#pragma unroll
    for (int x = 0; x < NSUB; ++x) {
        const int cx = scnt[x];
        const int ox = soff[x];
        const unsigned int* sp = stage + (size_t)(b * NSUB + x) * CAPS;
        for (int i = t; i < cx; i += 256) {
            unsigned int v = sp[i];
            ent[ox + i] = v;
            atomicAdd(&hist[v >> 24], 1);
        }
    }
    __syncthreads();
    const int c = soff[NSUB];

    int lane = t & 63, w = t >> 6;
    int v = (t < BSZ) ? hist[t] : 0;
    int inc = v;
#pragma unroll
    for (int off = 1; off < 64; off <<= 1) {
        int u = __shfl_up(inc, off, 64);
        if (lane >= off) inc += u;
    }
    if (t == 63) wtot = inc;
    __syncthreads();
    int excl = inc - v + ((w == 1) ? wtot : 0);
    if (t < BSZ) {
        int node = n0 + t;
        if (node <= NNODES) rowstart[node] = base + excl;
    }
    __syncthreads();
    if (t < BSZ) hist[t] = excl;
    __syncthreads();
    for (int i = t; i < c; i += 256) {
        unsigned int e = ent[i];
        int pos = atomicAdd(&hist[e >> 24], 1);
        csr_src[base + pos] = (int)(e & 0xFFFFFFu);
    }
}

// ===========================================================================
// Layer-0 aggregation + fused gemm1 -> bf16 h1 + layer-1 attention scalars.
// R11: h0 gathers are INT8 (uint2 = 8ch/lane, half the bytes); per-node
// scale folded into alpha (avs = alpha * scl[src], gathered in preamble
// parallel to aj — no extra serial latency). esum sums RAW alpha (exact).
// ===========================================================================
__global__ __launch_bounds__(256) void agg_gemm1(
        const int* __restrict__ rowstart, const int* __restrict__ csr_src,
        const float* __restrict__ aj, const float* __restrict__ scl,
        const float* __restrict__ ai, const unsigned int* __restrict__ h0q,
        const float* __restrict__ W1, const float* __restrict__ att1,
        unsigned short* __restrict__ h1b, float* __restrict__ ai1,
        float* __restrict__ aj1) {
    __shared__ float  W1L[64 * 68];     // oc-major, stride 68 (2-way banks: free)
    __shared__ float  rowbuf[4][64];    // per-wave combined row

    const int tid = threadIdx.x;
    for (int i = tid; i < 64 * 64; i += 256) {
        int oc = i >> 6, k = i & 63;
        W1L[oc * 68 + k] = (oc < 40) ? W1[oc * 64 + k] : 0.0f;
    }
    __syncthreads();

    const int lane = tid & 63;
    const int wid  = tid >> 6;
    const int n = blockIdx.x * 4 + wid;
    if (n >= NNODES) return;

    const int start = rowstart[n];
    const int end   = rowstart[n + 1];
    const float ain = ai[n];

    const int cg = lane & 7;            // 8 channel-groups of 8 ch
    const int sg = lane >> 3;           // 8 edge slots
    const int cgo = cg << 3;            // channel offset
    float4 accA = make_float4(0.f, 0.f, 0.f, 0.f);
    float4 accB = make_float4(0.f, 0.f, 0.f, 0.f);
    float  esum = 0.0f;

    for (int c = start; c < end; c += 64) {
        int rem = end - c;
        int cnt = (rem < 64) ? rem : 64;            // wave-uniform
        int   s    = 0;
        float ajv  = 0.0f;
        float sclv = 0.0f;
        if (lane < cnt) {
            s    = csr_src[c + lane];
            ajv  = aj[s];                           // own-edge gathers, parallel
            sclv = scl[s];                          // (scl table 0.4MB, L2-hot)
        }
        float tv = ain + ajv;
        tv = (tv > 0.0f) ? tv : 0.2f * tv;
        float av = (lane < cnt) ? __expf(tv) : 0.0f;
        esum += av;                                 // raw alpha, exactly once
        float avs = av * sclv;                      // scale folded into alpha
        for (int j0 = 0; j0 < cnt; j0 += 8) {       // uniform trips
            int j  = j0 + sg;
            int   sj = __shfl(s,   j, 64);          // full-wave shfl (R8 rule)
            float a  = __shfl(avs, j, 64);
            if (j < cnt) {
                uint2 hv = *(const uint2*)&h0q[(size_t)sj * 16 + cg * 2];
                accA.x = fmaf(a, (float)(signed char)(hv.x      ), accA.x);
                accA.y = fmaf(a, (float)(signed char)(hv.x >>  8), accA.y);
                accA.z = fmaf(a, (float)(signed char)(hv.x >> 16), accA.z);
                accA.w = fmaf(a, (float)(signed char)(hv.x >> 24), accA.w);
                accB.x = fmaf(a, (float)(signed char)(hv.y      ), accB.x);
                accB.y = fmaf(a, (float)(signed char)(hv.y >>  8), accB.y);
                accB.z = fmaf(a, (float)(signed char)(hv.y >> 16), accB.z);
                accB.w = fmaf(a, (float)(signed char)(hv.y >> 24), accB.w);
            }
        }
    }
#pragma unroll
    for (int off = 32; off > 0; off >>= 1) esum += __shfl_xor(esum, off, 64);
    const float inv = 1.0f / esum;
#pragma unroll
    for (int off = 8; off < 64; off <<= 1) {        // reduce over 8 edge slots
        accA.x += __shfl_xor(accA.x, off, 64);
        accA.y += __shfl_xor(accA.y, off, 64);
        accA.z += __shfl_xor(accA.z, off, 64);
        accA.w += __shfl_xor(accA.w, off, 64);
        accB.x += __shfl_xor(accB.x, off, 64);
        accB.y += __shfl_xor(accB.y, off, 64);
        accB.z += __shfl_xor(accB.z, off, 64);
        accB.w += __shfl_xor(accB.w, off, 64);
    }
    // normalize + relu, park row in LDS
    if (sg == 0) {
        float4 rA, rB;
        rA.x = fmaxf(accA.x * inv, 0.0f);
        rA.y = fmaxf(accA.y * inv, 0.0f);
        rA.z = fmaxf(accA.z * inv, 0.0f);
        rA.w = fmaxf(accA.w * inv, 0.0f);
        rB.x = fmaxf(accB.x * inv, 0.0f);
        rB.y = fmaxf(accB.y * inv, 0.0f);
        rB.z = fmaxf(accB.z * inv, 0.0f);
        rB.w = fmaxf(accB.w * inv, 0.0f);
        *(float4*)&rowbuf[wid][cgo]     = rA;
        *(float4*)&rowbuf[wid][cgo + 4] = rB;
    }

    // ---- fused gemm1: h1[n,oc] = sum_k row[k] * W1[oc,k] ----
    const int oc = lane;                 // lanes 40..63 hit zero-padded W1 rows
    float hacc = 0.0f;
#pragma unroll
    for (int k4 = 0; k4 < 16; ++k4) {
        float4 rv = *(const float4*)&rowbuf[wid][k4 * 4];       // broadcast
        float4 wv = *(const float4*)&W1L[oc * 68 + k4 * 4];
        hacc = fmaf(rv.x, wv.x, hacc);
        hacc = fmaf(rv.y, wv.y, hacc);
        hacc = fmaf(rv.z, wv.z, hacc);
        hacc = fmaf(rv.w, wv.w, hacc);
    }

    const bool ocOK = (oc < 40);
    if (ocOK) h1b[(size_t)n * 40 + oc] = f2bf(hacc);
    float pai = ocOK ? hacc * att1[oc]      : 0.0f;
    float paj = ocOK ? hacc * att1[40 + oc] : 0.0f;
#pragma unroll
    for (int off = 1; off < 64; off <<= 1) {
        pai += __shfl_xor(pai, off, 64);
        paj += __shfl_xor(paj, off, 64);
    }
    if (lane == 0) { ai1[n] = pai; aj1[n] = paj; }
}

// ===========================================================================
// Layer-1 aggregation (bf16 h1, 40 ch) + log_softmax (R10 structure).
// ===========================================================================
__global__ __launch_bounds__(256) void agg_lsm(
        const int* __restrict__ rowstart, const int* __restrict__ csr_src,
        const float* __restrict__ aj,
        const float* __restrict__ ai, const unsigned short* __restrict__ h1b,
        float* __restrict__ out) {
    const int lane = threadIdx.x & 63;
    const int wid  = threadIdx.x >> 6;
    const int n = blockIdx.x * 4 + wid;
    if (n >= NNODES) return;

    const int start = rowstart[n];
    const int end   = rowstart[n + 1];
    const float ain = ai[n];

    const int  cg   = lane & 7;
    const int  sg   = lane >> 3;
    const bool chOK = (cg < 5);         // 40 channels = 5 uint4 chunks
    float4 accA = make_float4(0.f, 0.f, 0.f, 0.f);
    float4 accB = make_float4(0.f, 0.f, 0.f, 0.f);
    float  esum = 0.0f;

    for (int c = start; c < end; c += 64) {
        int rem = end - c;
        int cnt = (rem < 64) ? rem : 64;
        int   s   = 0;
        float ajv = 0.0f;
        if (lane < cnt) {
            s   = csr_src[c + lane];
            ajv = aj[s];
        }
        float tv = ain + ajv;
        tv = (tv > 0.0f) ? tv : 0.2f * tv;
        float av = (lane < cnt) ? __expf(tv) : 0.0f;
        esum += av;                                 // each edge exactly once
        for (int j0 = 0; j0 < cnt; j0 += 8) {
            int j  = j0 + sg;
            int   sj = __shfl(s,  j, 64);           // full-wave shfl
            float a  = __shfl(av, j, 64);           // full-wave shfl
            if (chOK && j < cnt) {
                uint4 hv = *(const uint4*)&h1b[(unsigned)(sj * 40) + (cg << 3)];
                accA.x = fmaf(a, __uint_as_float(hv.x << 16),         accA.x);
                accA.y = fmaf(a, __uint_as_float(hv.x & 0xFFFF0000u), accA.y);
                accA.z = fmaf(a, __uint_as_float(hv.y << 16),         accA.z);
                accA.w = fmaf(a, __uint_as_float(hv.y & 0xFFFF0000u), accA.w);
                accB.x = fmaf(a, __uint_as_float(hv.z << 16),         accB.x);
                accB.y = fmaf(a, __uint_as_float(hv.z & 0xFFFF0000u), accB.y);
                accB.z = fmaf(a, __uint_as_float(hv.w << 16),         accB.z);
                accB.w = fmaf(a, __uint_as_float(hv.w & 0xFFFF0000u), accB.w);
            }
        }
    }
#pragma unroll
    for (int off = 32; off > 0; off >>= 1) esum += __shfl_xor(esum, off, 64);
    const float inv = 1.0f / esum;
#pragma unroll
    for (int off = 8; off < 64; off <<= 1) {
        accA.x += __shfl_xor(accA.x, off, 64);
        accA.y += __shfl_xor(accA.y, off, 64);
        accA.z += __shfl_xor(accA.z, off, 64);
        accA.w += __shfl_xor(accA.w, off, 64);
        accB.x += __shfl_xor(accB.x, off, 64);
        accB.y += __shfl_xor(accB.y, off, 64);
        accB.z += __shfl_xor(accB.z, off, 64);
        accB.w += __shfl_xor(accB.w, off, 64);
    }
    accA.x *= inv; accA.y *= inv; accA.z *= inv; accA.w *= inv;
    accB.x *= inv; accB.y *= inv; accB.z *= inv; accB.w *= inv;

    // log_softmax over 40 values (5 uint4 chunks in lanes cg<5; values
    // replicated across all 8 sg groups after the xor-reduce)
    float mx = -INFINITY;
    if (chOK) {
        mx = fmaxf(fmaxf(fmaxf(accA.x, accA.y), fmaxf(accA.z, accA.w)),
                   fmaxf(fmaxf(accB.x, accB.y), fmaxf(accB.z, accB.w)));
    }
#pragma unroll
    for (int off = 1; off < 8; off <<= 1) mx = fmaxf(mx, __shfl_xor(mx, off, 64));
    float sm = 0.0f;
    if (chOK) {
        sm = __expf(accA.x - mx) + __expf(accA.y - mx) +
             __expf(accA.z - mx) + __expf(accA.w - mx) +
             __expf(accB.x - mx) + __expf(accB.y - mx) +
             __expf(accB.z - mx) + __expf(accB.w - mx);
    }
#pragma unroll
    for (int off = 1; off < 8; off <<= 1) sm += __shfl_xor(sm, off, 64);
    float ls = mx + logf(sm);
    if (sg == 0 && chOK) {
        float4 oA = make_float4(accA.x - ls, accA.y - ls, accA.z - ls, accA.w - ls);
        float4 oB = make_float4(accB.x - ls, accB.y - ls, accB.z - ls, accB.w - ls);
        *(float4*)&out[(size_t)n * 40 + (cg << 3)]     = oA;
        *(float4*)&out[(size_t)n * 40 + (cg << 3) + 4] = oB;
    }
}

// ===========================================================================
extern "C" void kernel_launch(void* const* d_in, const int* in_sizes, int n_in,
                              void* d_out, int out_size, void* d_ws, size_t ws_size,
                              hipStream_t stream) {
    const float* x    = (const float*)d_in[0];
    const int*   ei   = (const int*)  d_in[1];
    const float* W0   = (const float*)d_in[2];
    const float* att0 = (const float*)d_in[3];
    const float* W1   = (const float*)d_in[4];
    const float* att1 = (const float*)d_in[5];
    float* out = (float*)d_out;

    // workspace layout (16B-aligned segments)
    int* wi = (int*)d_ws;
    int*  cnt      = wi;                        // 100352
    int*  bstart   = cnt + 100352;              // 1024
    int*  rowstart = bstart + 1024;             // 100352
    unsigned int* stage = (unsigned int*)(rowstart + 100352);     // KBUCK*NSUB*CAPS
    int*  csr_src  = (int*)(stage + (size_t)KBUCK * NSUB * CAPS); // 1,700,096
    unsigned int* h0q = (unsigned int*)(csr_src + 1700096);       // N*16 uints (6.4MB int8)
    float* scl0 = (float*)(h0q + (size_t)NNODES * 16);            // 100352 (row scales)
    unsigned short* h1b = (unsigned short*)(scl0 + 100352);       // N*40 bf16 (8MB)
    float* fbase = (float*)(h1b + (size_t)NNODES * 40);           // -> 16B aligned
    float* ai0 = fbase;
    float* aj0 = ai0 + 100352;
    float* ai1 = aj0 + 100352;
    float* aj1 = ai1 + 100352;

    const int B = 256;
    const int aggGrid = (NNODES + 3) / 4;
    const int fusedGrid = (GGRP + BGRP) * 8;

    // ---- CSR build (bucket half) fused with layer-0 GEMM (independent) ----
    zero_cnt<<<(KBUCK * NSUB * CPAD + B - 1) / B, B, 0, stream>>>(cnt);
    fusedA<<<fusedGrid, B, 0, stream>>>(ei, cnt, stage, x, W0, att0,
                                        h0q, scl0, ai0, aj0);
    bucket_scan<<<1, 1024, 0, stream>>>(cnt, bstart);
    bucket_scatter<<<KBUCK, B, 0, stream>>>(cnt, bstart, stage, rowstart, csr_src);

    // ---- layer-0 aggregation + fused gemm1 + layer-1 attention scalars ----
    agg_gemm1<<<aggGrid, B, 0, stream>>>(rowstart, csr_src, aj0, scl0, ai0, h0q,
                                         W1, att1, h1b, ai1, aj1);

    // ---- layer-1 aggregation + log_softmax ----
    agg_lsm<<<aggGrid, B, 0, stream>>>(rowstart, csr_src, aj1, ai1, h1b, out);
}